// Round 1
// baseline (832.495 us; speedup 1.0000x reference)
//
#include <hip/hip_runtime.h>
#include <math.h>

#define TLEN 2000
#define NSEQ 8       // B*C
#define NHEADS 8
#define KD 32
#define CHUNKN 500
#define NCHUNK 4
#define MROWS 16000  // NSEQ*TLEN
#define SCALING 0.1767766952966369f

// ---------------------------------------------------------------- tables
__global__ __launch_bounds__(256) void tab_kernel(float* __restrict__ sinT,
                                                  float* __restrict__ cosT) {
    int idx = blockIdx.x * 256 + threadIdx.x;
    if (idx >= TLEN * KD) return;
    int t = idx >> 5, j = idx & 31;
    float ang = powf(10000.0f, -(float)(j >> 1) / 15.0f);
    float th = (float)t * ang;
    sinT[idx] = sinf(th);
    cosT[idx] = cosf(th);
}

// ---------------------------------------------------------------- layernorm
__global__ __launch_bounds__(256) void ln_kernel(const float* __restrict__ x,
                                                 const float* __restrict__ gam,
                                                 const float* __restrict__ bet,
                                                 float* __restrict__ y, int rows) {
    int wid = threadIdx.x >> 6, lane = threadIdx.x & 63;
    int row = blockIdx.x * 4 + wid;
    if (row >= rows) return;
    const float* xr = x + (size_t)row * 256;
    float4 v = *(const float4*)(xr + lane * 4);
    float s = v.x + v.y + v.z + v.w;
    #pragma unroll
    for (int o = 32; o; o >>= 1) s += __shfl_xor(s, o);
    float mu = s * (1.0f / 256.0f);
    float dx = v.x - mu, dy = v.y - mu, dz = v.z - mu, dw = v.w - mu;
    float ss = dx * dx + dy * dy + dz * dz + dw * dw;
    #pragma unroll
    for (int o = 32; o; o >>= 1) ss += __shfl_xor(ss, o);
    float rstd = rsqrtf(ss * (1.0f / 256.0f) + 1e-5f);
    float4 g4 = *(const float4*)(gam + lane * 4);
    float4 b4 = *(const float4*)(bet + lane * 4);
    float4 o4;
    o4.x = dx * rstd * g4.x + b4.x;
    o4.y = dy * rstd * g4.y + b4.y;
    o4.z = dz * rstd * g4.z + b4.z;
    o4.w = dw * rstd * g4.w + b4.w;
    *(float4*)(y + (size_t)row * 256 + lane * 4) = o4;
}

// ---------------------------------------------------------------- GEMM (y = A @ W.T), K=256
// MODE 0: proj -> qr/kr (rotary, k*SCALING), v, g     MODE 1: out += resid
// MODE 2: qkv + bias, q*hd^-.5, split into 3 dsts     MODE 3: out = resid + acc + bias
template <int MODE>
__global__ __launch_bounds__(256) void gemm_fused(
    const float* __restrict__ A, const float* __restrict__ W0,
    const float* __restrict__ W1, const float* __restrict__ W2,
    const float* __restrict__ W3, const float* __restrict__ sinT,
    const float* __restrict__ cosT, const float* __restrict__ bias,
    const float* __restrict__ resid, float* __restrict__ D0,
    float* __restrict__ D1, float* __restrict__ D2, float* __restrict__ D3) {
    __shared__ float As[32][68];
    __shared__ float Bs[32][68];
    const int tid = threadIdx.x;
    const int tx = tid & 15, ty = tid >> 4;
    const int m0 = blockIdx.y * 64, n0 = blockIdx.x * 64;
    const float* Wb;
    if constexpr (MODE == 0) {
        const int w = n0 >> 8;
        const float* Ws = (w == 0) ? W0 : (w == 1) ? W1 : (w == 2) ? W2 : W3;
        Wb = Ws + (size_t)(n0 & 255) * 256;
    } else {
        Wb = W0 + (size_t)n0 * 256;
    }
    const int lm = tid >> 3;
    const int lk = (tid & 7) << 2;
    float acc[4][4];
    #pragma unroll
    for (int r = 0; r < 4; ++r)
        #pragma unroll
        for (int c = 0; c < 4; ++c) acc[r][c] = 0.f;

    for (int kt = 0; kt < 256; kt += 32) {
        float4 a0 = *(const float4*)&A[(size_t)(m0 + lm) * 256 + kt + lk];
        float4 a1 = *(const float4*)&A[(size_t)(m0 + lm + 32) * 256 + kt + lk];
        float4 b0 = *(const float4*)&Wb[(size_t)lm * 256 + kt + lk];
        float4 b1 = *(const float4*)&Wb[(size_t)(lm + 32) * 256 + kt + lk];
        __syncthreads();
        As[lk + 0][lm] = a0.x; As[lk + 1][lm] = a0.y; As[lk + 2][lm] = a0.z; As[lk + 3][lm] = a0.w;
        As[lk + 0][lm + 32] = a1.x; As[lk + 1][lm + 32] = a1.y; As[lk + 2][lm + 32] = a1.z; As[lk + 3][lm + 32] = a1.w;
        Bs[lk + 0][lm] = b0.x; Bs[lk + 1][lm] = b0.y; Bs[lk + 2][lm] = b0.z; Bs[lk + 3][lm] = b0.w;
        Bs[lk + 0][lm + 32] = b1.x; Bs[lk + 1][lm + 32] = b1.y; Bs[lk + 2][lm + 32] = b1.z; Bs[lk + 3][lm + 32] = b1.w;
        __syncthreads();
        #pragma unroll
        for (int kk = 0; kk < 32; ++kk) {
            float4 av = *(const float4*)&As[kk][ty * 4];
            float4 bv = *(const float4*)&Bs[kk][tx * 4];
            float ar[4] = {av.x, av.y, av.z, av.w};
            float br[4] = {bv.x, bv.y, bv.z, bv.w};
            #pragma unroll
            for (int r = 0; r < 4; ++r)
                #pragma unroll
                for (int c = 0; c < 4; ++c) acc[r][c] = fmaf(ar[r], br[c], acc[r][c]);
        }
    }

    const int gr0 = m0 + ty * 4;
    const int gc0 = n0 + tx * 4;
    if constexpr (MODE == 0) {
        const int w = n0 >> 8;
        const int cb = gc0 & 255;
        const int h = cb >> 5, d0 = cb & 31;
        #pragma unroll
        for (int r = 0; r < 4; ++r) {
            int i = gr0 + r;
            int b = i / TLEN, t = i % TLEN;
            if (w <= 1) {
                float sc = (w == 1) ? SCALING : 1.0f;
                float y0 = acc[r][0] * sc, y1 = acc[r][1] * sc;
                float y2 = acc[r][2] * sc, y3 = acc[r][3] * sc;
                const float* cp = cosT + t * 32 + d0;
                const float* sp = sinT + t * 32 + d0;
                float o0 = y0 * cp[0] - y1 * sp[0];
                float o1 = y1 * cp[1] + y0 * sp[1];
                float o2 = y2 * cp[2] - y3 * sp[2];
                float o3 = y3 * cp[3] + y2 * sp[3];
                float* dst = ((w == 0) ? D0 : D1) +
                             ((size_t)(b * NHEADS + h) * TLEN + t) * KD + d0;
                dst[0] = o0; dst[1] = o1; dst[2] = o2; dst[3] = o3;
            } else if (w == 2) {
                float* dst = D2 + ((size_t)(b * NHEADS + h) * TLEN + t) * KD + d0;
                dst[0] = acc[r][0]; dst[1] = acc[r][1]; dst[2] = acc[r][2]; dst[3] = acc[r][3];
            } else {
                float* dst = D3 + (size_t)i * 256 + cb;
                dst[0] = acc[r][0]; dst[1] = acc[r][1]; dst[2] = acc[r][2]; dst[3] = acc[r][3];
            }
        }
    } else if constexpr (MODE == 1) {
        #pragma unroll
        for (int r = 0; r < 4; ++r) {
            int i = gr0 + r;
            float* dst = D0 + (size_t)i * 256 + gc0;
            const float* rp = resid + (size_t)i * 256 + gc0;
            #pragma unroll
            for (int c = 0; c < 4; ++c) dst[c] = rp[c] + acc[r][c];
        }
    } else if constexpr (MODE == 2) {
        const int w = n0 >> 8;
        const int cb = gc0 & 255;
        float bs[4] = {bias[gc0], bias[gc0 + 1], bias[gc0 + 2], bias[gc0 + 3]};
        float* Dsel = (w == 0) ? D0 : (w == 1) ? D1 : D2;
        float qs = (w == 0) ? SCALING : 1.0f;
        #pragma unroll
        for (int r = 0; r < 4; ++r) {
            int i = gr0 + r;
            float* dst = Dsel + (size_t)i * 256 + cb;
            #pragma unroll
            for (int c = 0; c < 4; ++c) dst[c] = (acc[r][c] + bs[c]) * qs;
        }
    } else {
        float bs[4] = {bias[gc0], bias[gc0 + 1], bias[gc0 + 2], bias[gc0 + 3]};
        #pragma unroll
        for (int r = 0; r < 4; ++r) {
            int i = gr0 + r;
            float* dst = D0 + (size_t)i * 256 + gc0;
            const float* rp = resid + (size_t)i * 256 + gc0;
            #pragma unroll
            for (int c = 0; c < 4; ++c) dst[c] = rp[c] + acc[r][c] + bs[c];
        }
    }
}

// ---------------------------------------------------------------- kv per chunk
__global__ __launch_bounds__(256) void kv_kernel(const float* __restrict__ kr,
                                                 const float* __restrict__ v,
                                                 float* __restrict__ kv) {
    int blk = blockIdx.x;
    int b = blk >> 5, n = (blk >> 3) & 3, h = blk & 7;
    int tid = threadIdx.x;
    int k = tid >> 3, d0 = (tid & 7) * 4;
    float dec = logf(1.0f - exp2f(-5.0f - (float)h));
    float lrs = (1.0f - expf(dec * (float)CHUNKN)) / (1.0f - expf(dec));
    float invl = 1.0f / lrs;
    const float* krb = kr + ((size_t)(b * NHEADS + h) * TLEN + n * CHUNKN) * KD;
    const float* vb = v + ((size_t)(b * NHEADS + h) * TLEN + n * CHUNKN) * KD;
    float a0 = 0, a1 = 0, a2 = 0, a3 = 0;
    for (int j = 0; j < CHUNKN; ++j) {
        float kj = krb[(size_t)j * KD + k];
        float vd = expf(dec * (float)(CHUNKN - 1 - j)) * invl;
        float w = kj * vd;
        float4 vv = *(const float4*)(vb + (size_t)j * KD + d0);
        a0 = fmaf(w, vv.x, a0); a1 = fmaf(w, vv.y, a1);
        a2 = fmaf(w, vv.z, a2); a3 = fmaf(w, vv.w, a3);
    }
    float* dst = kv + ((size_t)(b * NCHUNK + n) * NHEADS + h) * 1024 + k * 32 + d0;
    dst[0] = a0; dst[1] = a1; dst[2] = a2; dst[3] = a3;
}

// ---------------------------------------------------------------- cross-chunk scan
__global__ __launch_bounds__(256) void scan_kernel(const float* __restrict__ kv,
                                                   float* __restrict__ rec,
                                                   float* __restrict__ sig) {
    __shared__ float cs[32];
    __shared__ float ssig;
    int blk = blockIdx.x;
    int b = blk >> 3, h = blk & 7;
    int tid = threadIdx.x;
    float dec = logf(1.0f - exp2f(-5.0f - (float)h));
    float cd = expf(dec * (float)CHUNKN);
    float S0 = 0, S1 = 0, S2 = 0, S3 = 0;
    float sigma = 1.0f;
    for (int n = 0; n < NCHUNK; ++n) {
        size_t base = ((size_t)(b * NCHUNK + n) * NHEADS + h) * 1024;
        rec[base + tid] = S0;
        rec[base + tid + 256] = S1;
        rec[base + tid + 512] = S2;
        rec[base + tid + 768] = S3;
        if (tid == 0) sig[(b * NCHUNK + n) * NHEADS + h] = sigma;
        S0 = S0 * cd + kv[base + tid];
        S1 = S1 * cd + kv[base + tid + 256];
        S2 = S2 * cd + kv[base + tid + 512];
        S3 = S3 * cd + kv[base + tid + 768];
        if (tid < 32) cs[tid] = 0.f;
        __syncthreads();
        float part = fabsf(S0) + fabsf(S1) + fabsf(S2) + fabsf(S3);
        atomicAdd(&cs[tid & 31], part);
        __syncthreads();
        if (tid == 0) {
            float m = cs[0];
            for (int d = 1; d < 32; ++d) m = fmaxf(m, cs[d]);
            ssig = fmaxf(m, 1.0f);
        }
        __syncthreads();
        sigma = ssig;
    }
}

// ---------------------------------------------------------------- retention core
__global__ __launch_bounds__(512) void ret_core(
    const float* __restrict__ qr, const float* __restrict__ kr,
    const float* __restrict__ v, const float* __restrict__ g,
    const float* __restrict__ rec, const float* __restrict__ sig,
    float* __restrict__ abuf) {
    __shared__ float vS[CHUNKN * KD];
    const int blk = blockIdx.x;
    const int b = blk >> 5, n = (blk >> 3) & 3, h = blk & 7;
    const int tid = threadIdx.x;
    const size_t cbase = ((size_t)(b * NHEADS + h) * TLEN + n * CHUNKN) * KD;
    const float4* vg4 = (const float4*)(v + cbase);
    float4* vS4w = (float4*)vS;
    for (int idx = tid; idx < CHUNKN * KD / 4; idx += 512) vS4w[idx] = vg4[idx];
    __syncthreads();
    const int wid = tid >> 6, lane = tid & 63;
    const int i = (wid < 4) ? (wid * 64 + lane) : (256 + (7 - wid) * 64 + lane);
    if (i >= CHUNKN) return;
    const float dec = logf(1.0f - exp2f(-5.0f - (float)h));
    const float er = expf(dec);
    const float inv1mr = 1.0f / (1.0f - er);
    const float lrs = (1.0f - expf(dec * (float)CHUNKN)) * inv1mr;
    const float sgp = sig[(b * NCHUNK + n) * NHEADS + h];
    const float4* q4 = (const float4*)(qr + cbase + (size_t)i * KD);
    float4 q[8];
    #pragma unroll
    for (int r = 0; r < 8; ++r) q[r] = q4[r];
    float4 o[8];
    #pragma unroll
    for (int r = 0; r < 8; ++r) o[r] = make_float4(0.f, 0.f, 0.f, 0.f);
    float absacc = 0.f;
    const float ndec = -dec;
    const float* krb = kr + cbase;
    const float4* vS4 = (const float4*)vS;
    for (int j = 0; j <= i; ++j) {
        const float4* k4 = (const float4*)(krb + (size_t)j * KD);
        float a0 = 0, a1 = 0, a2 = 0, a3 = 0;
        #pragma unroll
        for (int r = 0; r < 8; ++r) {
            float4 kk = k4[r];
            a0 = fmaf(q[r].x, kk.x, a0);
            a1 = fmaf(q[r].y, kk.y, a1);
            a2 = fmaf(q[r].z, kk.z, a2);
            a3 = fmaf(q[r].w, kk.w, a3);
        }
        float dot = (a0 + a1) + (a2 + a3);
        float ej = expf(ndec * (float)j);
        float w = dot * ej;
        absacc += fabsf(w);
        #pragma unroll
        for (int r = 0; r < 8; ++r) {
            float4 vv = vS4[j * 8 + r];
            o[r].x = fmaf(w, vv.x, o[r].x);
            o[r].y = fmaf(w, vv.y, o[r].y);
            o[r].z = fmaf(w, vv.z, o[r].z);
            o[r].w = fmaf(w, vv.w, o[r].w);
        }
    }
    float rowsum = (1.0f - expf(dec * (float)(i + 1))) * inv1mr;
    float scale_i = sqrtf(rowsum);
    float inv_scale = 1.0f / scale_i;
    float f_i = expf(dec * (float)i) * inv_scale;
    float inner_scale = fmaxf(absacc * f_i, 1.0f);
    float all_scale = fmaxf(inner_scale, sgp);
    #pragma unroll
    for (int r = 0; r < 8; ++r) {
        o[r].x *= f_i; o[r].y *= f_i; o[r].z *= f_i; o[r].w *= f_i;
    }
    // cross term: o += (q * qdec) @ S_prev
    float qdec = expf(dec * (float)(i + 1)) * lrs * inv_scale;
    const float* sp = rec + ((size_t)(b * NCHUNK + n) * NHEADS + h) * 1024;
    #pragma unroll
    for (int kq = 0; kq < 8; ++kq) {
        float qc[4] = {q[kq].x, q[kq].y, q[kq].z, q[kq].w};
        #pragma unroll
        for (int c = 0; c < 4; ++c) {
            float coef = qc[c] * qdec;
            const float4* sr = (const float4*)(sp + (kq * 4 + c) * 32);
            #pragma unroll
            for (int r = 0; r < 8; ++r) {
                float4 sv = sr[r];
                o[r].x = fmaf(coef, sv.x, o[r].x);
                o[r].y = fmaf(coef, sv.y, o[r].y);
                o[r].z = fmaf(coef, sv.z, o[r].z);
                o[r].w = fmaf(coef, sv.w, o[r].w);
            }
        }
    }
    float inv_all = 1.0f / all_scale;
    float ms = 0.f;
    #pragma unroll
    for (int r = 0; r < 8; ++r) {
        o[r].x *= inv_all; o[r].y *= inv_all; o[r].z *= inv_all; o[r].w *= inv_all;
        ms += o[r].x * o[r].x + o[r].y * o[r].y + o[r].z * o[r].z + o[r].w * o[r].w;
    }
    float rn = rsqrtf(ms * (1.0f / 32.0f) + 1e-6f);
    const int tg = n * CHUNKN + i;
    const float4* gp = (const float4*)(g + ((size_t)b * TLEN + tg) * 256 + h * KD);
    float4* ap = (float4*)(abuf + ((size_t)b * TLEN + tg) * 256 + h * KD);
    #pragma unroll
    for (int r = 0; r < 8; ++r) {
        float4 gv = gp[r];
        float4 outv;
        float g0 = gv.x, g1 = gv.y, g2 = gv.z, g3 = gv.w;
        outv.x = (g0 / (1.0f + expf(-g0))) * (o[r].x * rn);
        outv.y = (g1 / (1.0f + expf(-g1))) * (o[r].y * rn);
        outv.z = (g2 / (1.0f + expf(-g2))) * (o[r].z * rn);
        outv.w = (g3 / (1.0f + expf(-g3))) * (o[r].w * rn);
        ap[r] = outv;
    }
}

// ---------------------------------------------------------------- tiny MHA (seq len 4)
__global__ __launch_bounds__(256) void mha_attn(const float* __restrict__ qh,
                                                const float* __restrict__ kh,
                                                const float* __restrict__ vh,
                                                float* __restrict__ oh) {
    int gidx = blockIdx.x * 256 + threadIdx.x;
    if (gidx >= 2 * TLEN * NHEADS * 4) return;
    int i = gidx & 3;
    int h = (gidx >> 2) & 7;
    int rest = gidx >> 5;  // b*2000 + t
    int t = rest % TLEN;
    int b = rest / TLEN;
    size_t rows[4];
    #pragma unroll
    for (int c = 0; c < 4; ++c) rows[c] = ((size_t)(b * 4 + c) * TLEN + t);
    const float4* q4 = (const float4*)(qh + rows[i] * 256 + h * 32);
    float4 q[8];
    #pragma unroll
    for (int r = 0; r < 8; ++r) q[r] = q4[r];
    float s[4];
    #pragma unroll
    for (int j = 0; j < 4; ++j) {
        const float4* k4 = (const float4*)(kh + rows[j] * 256 + h * 32);
        float a0 = 0, a1 = 0, a2 = 0, a3 = 0;
        #pragma unroll
        for (int r = 0; r < 8; ++r) {
            float4 kk = k4[r];
            a0 = fmaf(q[r].x, kk.x, a0);
            a1 = fmaf(q[r].y, kk.y, a1);
            a2 = fmaf(q[r].z, kk.z, a2);
            a3 = fmaf(q[r].w, kk.w, a3);
        }
        s[j] = (a0 + a1) + (a2 + a3);
    }
    float m = fmaxf(fmaxf(s[0], s[1]), fmaxf(s[2], s[3]));
    float p[4], den = 0.f;
    #pragma unroll
    for (int j = 0; j < 4; ++j) { p[j] = expf(s[j] - m); den += p[j]; }
    float inv = 1.0f / den;
    float4 o[8];
    #pragma unroll
    for (int r = 0; r < 8; ++r) o[r] = make_float4(0.f, 0.f, 0.f, 0.f);
    #pragma unroll
    for (int j = 0; j < 4; ++j) {
        float wj = p[j] * inv;
        const float4* v4 = (const float4*)(vh + rows[j] * 256 + h * 32);
        #pragma unroll
        for (int r = 0; r < 8; ++r) {
            float4 vv = v4[r];
            o[r].x = fmaf(wj, vv.x, o[r].x);
            o[r].y = fmaf(wj, vv.y, o[r].y);
            o[r].z = fmaf(wj, vv.z, o[r].z);
            o[r].w = fmaf(wj, vv.w, o[r].w);
        }
    }
    float4* d4 = (float4*)(oh + rows[i] * 256 + h * 32);
    #pragma unroll
    for (int r = 0; r < 8; ++r) d4[r] = o[r];
}

// ---------------------------------------------------------------- launch
extern "C" void kernel_launch(void* const* d_in, const int* in_sizes, int n_in,
                              void* d_out, int out_size, void* d_ws, size_t ws_size,
                              hipStream_t stream) {
    (void)in_sizes; (void)n_in; (void)out_size; (void)ws_size;
    const float* x    = (const float*)d_in[0];
    const float* ln1g = (const float*)d_in[1];
    const float* ln1b = (const float*)d_in[2];
    const float* ln2g = (const float*)d_in[3];
    const float* ln2b = (const float*)d_in[4];
    const float* qw   = (const float*)d_in[5];
    const float* kw   = (const float*)d_in[6];
    const float* vw   = (const float*)d_in[7];
    const float* gw   = (const float*)d_in[8];
    const float* ow   = (const float*)d_in[9];
    const float* in_w = (const float*)d_in[10];
    const float* in_b = (const float*)d_in[11];
    const float* outw = (const float*)d_in[12];
    const float* outb = (const float*)d_in[13];
    float* out = (float*)d_out;
    float* ws = (float*)d_ws;

    // workspace layout (floats)
    constexpr size_t O_SIN = 0;
    constexpr size_t O_COS = O_SIN + (size_t)TLEN * KD;           // 64000
    constexpr size_t O_A   = O_COS + (size_t)TLEN * KD;           // xn / abuf / q-hat
    constexpr size_t O_B   = O_A + 4096000;                       // qr / x2
    constexpr size_t O_C   = O_B + 4096000;                       // kr / yn / attnout
    constexpr size_t O_D   = O_C + 4096000;                       // v  / k-hat
    constexpr size_t O_E   = O_D + 4096000;                       // g  / v-hat
    constexpr size_t O_KV  = O_E + 4096000;                       // 262144
    constexpr size_t O_REC = O_KV + 262144;                       // 262144
    constexpr size_t O_SIG = O_REC + 262144;                      // 256
    // total = 21,132,544 floats = 84.5 MB

    float* sinT = ws + O_SIN;
    float* cosT = ws + O_COS;
    float* bufA = ws + O_A;
    float* bufB = ws + O_B;
    float* bufC = ws + O_C;
    float* bufD = ws + O_D;
    float* bufE = ws + O_E;
    float* kvb  = ws + O_KV;
    float* recb = ws + O_REC;
    float* sigb = ws + O_SIG;

    // 0) rotary tables
    tab_kernel<<<250, 256, 0, stream>>>(sinT, cosT);
    // 1) LN1: x -> xn (bufA)
    ln_kernel<<<MROWS / 4, 256, 0, stream>>>(x, ln1g, ln1b, bufA, MROWS);
    // 2) projections: xn @ [qw kw vw gw].T -> qr(B) kr(C) v(D) g(E)
    gemm_fused<0><<<dim3(16, MROWS / 64), 256, 0, stream>>>(
        bufA, qw, kw, vw, gw, sinT, cosT, nullptr, nullptr, bufB, bufC, bufD, bufE);
    // 3) kv per chunk
    kv_kernel<<<256, 256, 0, stream>>>(bufC, bufD, kvb);
    // 4) cross-chunk scan -> rec, sig
    scan_kernel<<<64, 256, 0, stream>>>(kvb, recb, sigb);
    // 5) retention core -> abuf (bufA, silu(g)*norm(out))
    ret_core<<<256, 512, 0, stream>>>(bufB, bufC, bufD, bufE, recb, sigb, bufA);
    // 6) out-proj + residual: x + abuf @ ow.T -> x2 (bufB)
    gemm_fused<1><<<dim3(4, MROWS / 64), 256, 0, stream>>>(
        bufA, ow, nullptr, nullptr, nullptr, nullptr, nullptr, nullptr, x,
        bufB, nullptr, nullptr, nullptr);
    // 7) LN2: x2 -> yn (bufC)
    ln_kernel<<<MROWS / 4, 256, 0, stream>>>(bufB, ln2g, ln2b, bufC, MROWS);
    // 8) qkv: yn @ in_w.T + in_b -> qhat(A) khat(D) vhat(E)
    gemm_fused<2><<<dim3(12, MROWS / 64), 256, 0, stream>>>(
        bufC, in_w, nullptr, nullptr, nullptr, nullptr, nullptr, in_b, nullptr,
        bufA, bufD, bufE, nullptr);
    // 9) tiny attention -> attnout (bufC)
    mha_attn<<<500, 256, 0, stream>>>(bufA, bufD, bufE, bufC);
    // 10) final: x2 + attnout @ out_w.T + out_b -> d_out
    gemm_fused<3><<<dim3(4, MROWS / 64), 256, 0, stream>>>(
        bufC, outw, nullptr, nullptr, nullptr, nullptr, nullptr, outb, bufB,
        out, nullptr, nullptr, nullptr);
}

// Round 3
// 552.578 us; speedup vs baseline: 1.5066x; 1.5066x over previous
//
#include <hip/hip_runtime.h>
#include <math.h>

#define TLEN 2000
#define NSEQ 8       // B*C
#define NHEADS 8
#define KD 32
#define CHUNKN 500
#define NCHUNK 4
#define MROWS 16000  // NSEQ*TLEN
#define SCALING 0.1767766952966369f

// ---------------------------------------------------------------- tables
__global__ __launch_bounds__(256) void tab_kernel(float* __restrict__ sinT,
                                                  float* __restrict__ cosT) {
    int idx = blockIdx.x * 256 + threadIdx.x;
    if (idx >= TLEN * KD) return;
    int t = idx >> 5, j = idx & 31;
    float ang = powf(10000.0f, -(float)(j >> 1) / 15.0f);
    float th = (float)t * ang;
    sinT[idx] = sinf(th);
    cosT[idx] = cosf(th);
}

// ---------------------------------------------------------------- layernorm
__global__ __launch_bounds__(256) void ln_kernel(const float* __restrict__ x,
                                                 const float* __restrict__ gam,
                                                 const float* __restrict__ bet,
                                                 float* __restrict__ y, int rows) {
    int wid = threadIdx.x >> 6, lane = threadIdx.x & 63;
    int row = blockIdx.x * 4 + wid;
    if (row >= rows) return;
    const float* xr = x + (size_t)row * 256;
    float4 v = *(const float4*)(xr + lane * 4);
    float s = v.x + v.y + v.z + v.w;
    #pragma unroll
    for (int o = 32; o; o >>= 1) s += __shfl_xor(s, o);
    float mu = s * (1.0f / 256.0f);
    float dx = v.x - mu, dy = v.y - mu, dz = v.z - mu, dw = v.w - mu;
    float ss = dx * dx + dy * dy + dz * dz + dw * dw;
    #pragma unroll
    for (int o = 32; o; o >>= 1) ss += __shfl_xor(ss, o);
    float rstd = rsqrtf(ss * (1.0f / 256.0f) + 1e-5f);
    float4 g4 = *(const float4*)(gam + lane * 4);
    float4 b4 = *(const float4*)(bet + lane * 4);
    float4 o4;
    o4.x = dx * rstd * g4.x + b4.x;
    o4.y = dy * rstd * g4.y + b4.y;
    o4.z = dz * rstd * g4.z + b4.z;
    o4.w = dw * rstd * g4.w + b4.w;
    *(float4*)(y + (size_t)row * 256 + lane * 4) = o4;
}

// ---------------------------------------------------------------- GEMM (y = A @ W.T), K=256
template <int MODE>
__global__ __launch_bounds__(256) void gemm_fused(
    const float* __restrict__ A, const float* __restrict__ W0,
    const float* __restrict__ W1, const float* __restrict__ W2,
    const float* __restrict__ W3, const float* __restrict__ sinT,
    const float* __restrict__ cosT, const float* __restrict__ bias,
    const float* __restrict__ resid, float* __restrict__ D0,
    float* __restrict__ D1, float* __restrict__ D2, float* __restrict__ D3) {
    __shared__ float As[32][68];
    __shared__ float Bs[32][68];
    const int tid = threadIdx.x;
    const int tx = tid & 15, ty = tid >> 4;
    const int m0 = blockIdx.y * 64, n0 = blockIdx.x * 64;
    const float* Wb;
    if constexpr (MODE == 0) {
        const int w = n0 >> 8;
        const float* Ws = (w == 0) ? W0 : (w == 1) ? W1 : (w == 2) ? W2 : W3;
        Wb = Ws + (size_t)(n0 & 255) * 256;
    } else {
        Wb = W0 + (size_t)n0 * 256;
    }
    const int lm = tid >> 3;
    const int lk = (tid & 7) << 2;
    float acc[4][4];
    #pragma unroll
    for (int r = 0; r < 4; ++r)
        #pragma unroll
        for (int c = 0; c < 4; ++c) acc[r][c] = 0.f;

    for (int kt = 0; kt < 256; kt += 32) {
        float4 a0 = *(const float4*)&A[(size_t)(m0 + lm) * 256 + kt + lk];
        float4 a1 = *(const float4*)&A[(size_t)(m0 + lm + 32) * 256 + kt + lk];
        float4 b0 = *(const float4*)&Wb[(size_t)lm * 256 + kt + lk];
        float4 b1 = *(const float4*)&Wb[(size_t)(lm + 32) * 256 + kt + lk];
        __syncthreads();
        As[lk + 0][lm] = a0.x; As[lk + 1][lm] = a0.y; As[lk + 2][lm] = a0.z; As[lk + 3][lm] = a0.w;
        As[lk + 0][lm + 32] = a1.x; As[lk + 1][lm + 32] = a1.y; As[lk + 2][lm + 32] = a1.z; As[lk + 3][lm + 32] = a1.w;
        Bs[lk + 0][lm] = b0.x; Bs[lk + 1][lm] = b0.y; Bs[lk + 2][lm] = b0.z; Bs[lk + 3][lm] = b0.w;
        Bs[lk + 0][lm + 32] = b1.x; Bs[lk + 1][lm + 32] = b1.y; Bs[lk + 2][lm + 32] = b1.z; Bs[lk + 3][lm + 32] = b1.w;
        __syncthreads();
        #pragma unroll
        for (int kk = 0; kk < 32; ++kk) {
            float4 av = *(const float4*)&As[kk][ty * 4];
            float4 bv = *(const float4*)&Bs[kk][tx * 4];
            float ar[4] = {av.x, av.y, av.z, av.w};
            float br[4] = {bv.x, bv.y, bv.z, bv.w};
            #pragma unroll
            for (int r = 0; r < 4; ++r)
                #pragma unroll
                for (int c = 0; c < 4; ++c) acc[r][c] = fmaf(ar[r], br[c], acc[r][c]);
        }
    }

    const int gr0 = m0 + ty * 4;
    const int gc0 = n0 + tx * 4;
    if constexpr (MODE == 0) {
        const int w = n0 >> 8;
        const int cb = gc0 & 255;
        const int h = cb >> 5, d0 = cb & 31;
        #pragma unroll
        for (int r = 0; r < 4; ++r) {
            int i = gr0 + r;
            int b = i / TLEN, t = i % TLEN;
            if (w <= 1) {
                float sc = (w == 1) ? SCALING : 1.0f;
                float y0 = acc[r][0] * sc, y1 = acc[r][1] * sc;
                float y2 = acc[r][2] * sc, y3 = acc[r][3] * sc;
                const float* cp = cosT + t * 32 + d0;
                const float* sp = sinT + t * 32 + d0;
                float o0 = y0 * cp[0] - y1 * sp[0];
                float o1 = y1 * cp[1] + y0 * sp[1];
                float o2 = y2 * cp[2] - y3 * sp[2];
                float o3 = y3 * cp[3] + y2 * sp[3];
                float* dst = ((w == 0) ? D0 : D1) +
                             ((size_t)(b * NHEADS + h) * TLEN + t) * KD + d0;
                dst[0] = o0; dst[1] = o1; dst[2] = o2; dst[3] = o3;
            } else if (w == 2) {
                float* dst = D2 + ((size_t)(b * NHEADS + h) * TLEN + t) * KD + d0;
                dst[0] = acc[r][0]; dst[1] = acc[r][1]; dst[2] = acc[r][2]; dst[3] = acc[r][3];
            } else {
                float* dst = D3 + (size_t)i * 256 + cb;
                dst[0] = acc[r][0]; dst[1] = acc[r][1]; dst[2] = acc[r][2]; dst[3] = acc[r][3];
            }
        }
    } else if constexpr (MODE == 1) {
        #pragma unroll
        for (int r = 0; r < 4; ++r) {
            int i = gr0 + r;
            float* dst = D0 + (size_t)i * 256 + gc0;
            const float* rp = resid + (size_t)i * 256 + gc0;
            #pragma unroll
            for (int c = 0; c < 4; ++c) dst[c] = rp[c] + acc[r][c];
        }
    } else if constexpr (MODE == 2) {
        const int w = n0 >> 8;
        const int cb = gc0 & 255;
        float bs[4] = {bias[gc0], bias[gc0 + 1], bias[gc0 + 2], bias[gc0 + 3]};
        float* Dsel = (w == 0) ? D0 : (w == 1) ? D1 : D2;
        float qs = (w == 0) ? SCALING : 1.0f;
        #pragma unroll
        for (int r = 0; r < 4; ++r) {
            int i = gr0 + r;
            float* dst = Dsel + (size_t)i * 256 + cb;
            #pragma unroll
            for (int c = 0; c < 4; ++c) dst[c] = (acc[r][c] + bs[c]) * qs;
        }
    } else {
        float bs[4] = {bias[gc0], bias[gc0 + 1], bias[gc0 + 2], bias[gc0 + 3]};
        #pragma unroll
        for (int r = 0; r < 4; ++r) {
            int i = gr0 + r;
            float* dst = D0 + (size_t)i * 256 + gc0;
            const float* rp = resid + (size_t)i * 256 + gc0;
            #pragma unroll
            for (int c = 0; c < 4; ++c) dst[c] = rp[c] + acc[r][c] + bs[c];
        }
    }
}

// ---------------------------------------------------------------- kv partials (4 j-subchunks)
__global__ __launch_bounds__(256) void kvp_kernel(const float* __restrict__ kr,
                                                  const float* __restrict__ v,
                                                  float* __restrict__ kvp) {
    int blk = blockIdx.x;
    int sub = blk & 3, rest = blk >> 2;
    int b = rest >> 5, n = (rest >> 3) & 3, h = rest & 7;
    int tid = threadIdx.x;
    int k = tid >> 3, d0 = (tid & 7) * 4;
    float dec = logf(1.0f - exp2f(-5.0f - (float)h));
    float lrs = (1.0f - expf(dec * (float)CHUNKN)) / (1.0f - expf(dec));
    float invl = 1.0f / lrs;
    const float* krb = kr + ((size_t)(b * NHEADS + h) * TLEN + n * CHUNKN) * KD;
    const float* vb = v + ((size_t)(b * NHEADS + h) * TLEN + n * CHUNKN) * KD;
    float a0 = 0, a1 = 0, a2 = 0, a3 = 0;
    int j0 = sub * 125;
    for (int j = j0; j < j0 + 125; ++j) {
        float kj = krb[(size_t)j * KD + k];
        float vd = expf(dec * (float)(CHUNKN - 1 - j)) * invl;
        float w = kj * vd;
        float4 vv = *(const float4*)(vb + (size_t)j * KD + d0);
        a0 = fmaf(w, vv.x, a0); a1 = fmaf(w, vv.y, a1);
        a2 = fmaf(w, vv.z, a2); a3 = fmaf(w, vv.w, a3);
    }
    float* dst = kvp + ((size_t)rest * 4 + sub) * 1024 + k * 32 + d0;
    dst[0] = a0; dst[1] = a1; dst[2] = a2; dst[3] = a3;
}

// ---------------------------------------------------------------- cross-chunk scan
__global__ __launch_bounds__(256) void scan_kernel(const float* __restrict__ kvp,
                                                   float* __restrict__ rec,
                                                   float* __restrict__ sig) {
    __shared__ float cs[32];
    __shared__ float ssig;
    int blk = blockIdx.x;
    int b = blk >> 3, h = blk & 7;
    int tid = threadIdx.x;
    float dec = logf(1.0f - exp2f(-5.0f - (float)h));
    float cd = expf(dec * (float)CHUNKN);
    float S0 = 0, S1 = 0, S2 = 0, S3 = 0;
    float sigma = 1.0f;
    for (int n = 0; n < NCHUNK; ++n) {
        int rest = b * 32 + n * 8 + h;
        size_t rbase = (size_t)rest * 1024;
        size_t pbase = (size_t)rest * 4096;
        rec[rbase + tid] = S0;
        rec[rbase + tid + 256] = S1;
        rec[rbase + tid + 512] = S2;
        rec[rbase + tid + 768] = S3;
        if (tid == 0) sig[rest] = sigma;
        float k0 = 0, k1 = 0, k2 = 0, k3 = 0;
        #pragma unroll
        for (int s = 0; s < 4; ++s) {
            k0 += kvp[pbase + s * 1024 + tid];
            k1 += kvp[pbase + s * 1024 + tid + 256];
            k2 += kvp[pbase + s * 1024 + tid + 512];
            k3 += kvp[pbase + s * 1024 + tid + 768];
        }
        S0 = S0 * cd + k0;
        S1 = S1 * cd + k1;
        S2 = S2 * cd + k2;
        S3 = S3 * cd + k3;
        if (tid < 32) cs[tid] = 0.f;
        __syncthreads();
        float part = fabsf(S0) + fabsf(S1) + fabsf(S2) + fabsf(S3);
        atomicAdd(&cs[tid & 31], part);
        __syncthreads();
        if (tid == 0) {
            float m = cs[0];
            for (int d = 1; d < 32; ++d) m = fmaxf(m, cs[d]);
            ssig = fmaxf(m, 1.0f);
        }
        __syncthreads();
        sigma = ssig;
    }
}

// ---------------------------------------------------------------- retention core v2
// grid = 2048: blockIdx = band_rev*256 + chunk (heavy bands first)
// block = 256 threads: thread = (row-in-band il = tid>>2, colgroup c = tid&3)
__global__ __launch_bounds__(256, 8) void ret_core2(
    const float* __restrict__ qr, const float* __restrict__ kr,
    const float* __restrict__ v, const float* __restrict__ g,
    const float* __restrict__ rec, const float* __restrict__ sig,
    float* __restrict__ abuf) {
    __shared__ float tile[64 * 68];  // per j-tile: [jl][0..31]=k*e^{-dec j}, [32..63]=v (stride 68)
    const int u = 7 - (int)(blockIdx.x >> 8);
    const int chunk = blockIdx.x & 255;
    const int b = chunk >> 5, n = (chunk >> 3) & 3, h = chunk & 7;
    const int tid = threadIdx.x;
    const int c = tid & 3, il = tid >> 2;
    const int i = u * 64 + il;
    const bool active = (i < CHUNKN);
    const int lane = tid & 63;
    const int wid = tid >> 6;
    const int iwmax = min(u * 64 + wid * 16 + 15, CHUNKN - 1);
    const float dec = logf(1.0f - exp2f(-5.0f - (float)h));
    const float ndec = -dec;
    const size_t cbase = ((size_t)(b * NHEADS + h) * TLEN + n * CHUNKN) * KD;

    float4 q0 = make_float4(0.f, 0.f, 0.f, 0.f), q1 = q0;
    if (active) {
        const float4* qp = (const float4*)(qr + cbase + (size_t)i * KD + c * 8);
        q0 = qp[0]; q1 = qp[1];
    }
    float4 o0 = make_float4(0.f, 0.f, 0.f, 0.f), o1 = o0;
    float absacc = 0.f;

    for (int jt = 0; jt <= u; ++jt) {
        if (jt) __syncthreads();
        {   // stage tile jt: thread stages row il, slice c
            int jg = jt * 64 + il;
            float4 kx0 = make_float4(0.f, 0.f, 0.f, 0.f), kx1 = kx0, vx0 = kx0, vx1 = kx0;
            if (jg < CHUNKN) {
                const float4* kp = (const float4*)(kr + cbase + (size_t)jg * KD + c * 8);
                const float4* vp = (const float4*)(v + cbase + (size_t)jg * KD + c * 8);
                float ej = expf(ndec * (float)jg);
                kx0 = kp[0]; kx1 = kp[1];
                kx0.x *= ej; kx0.y *= ej; kx0.z *= ej; kx0.w *= ej;
                kx1.x *= ej; kx1.y *= ej; kx1.z *= ej; kx1.w *= ej;
                vx0 = vp[0]; vx1 = vp[1];
            }
            float4* tw = (float4*)(tile + il * 68);
            tw[c * 2] = kx0; tw[c * 2 + 1] = kx1;
            tw[8 + c * 2] = vx0; tw[8 + c * 2 + 1] = vx1;
        }
        __syncthreads();
        const int jcnt = min(63, iwmax - jt * 64);
        const int jbase = jt * 64;
        for (int jl = 0; jl <= jcnt; ++jl) {
            const float4* tp = (const float4*)(tile + jl * 68);
            float4 k0 = tp[c * 2], k1 = tp[c * 2 + 1];
            float4 v0 = tp[8 + c * 2], v1 = tp[8 + c * 2 + 1];
            float da = fmaf(q0.x, k0.x, q0.y * k0.y);
            float db = fmaf(q0.z, k0.z, q0.w * k0.w);
            float dcc = fmaf(q1.x, k1.x, q1.y * k1.y);
            float dd = fmaf(q1.z, k1.z, q1.w * k1.w);
            float d = (da + db) + (dcc + dd);
            d += __shfl_xor(d, 1);
            d += __shfl_xor(d, 2);
            float w = ((jbase + jl) <= i) ? d : 0.f;  // inactive rows: q=0 -> d=0
            absacc += fabsf(w);
            o0.x = fmaf(w, v0.x, o0.x); o0.y = fmaf(w, v0.y, o0.y);
            o0.z = fmaf(w, v0.z, o0.z); o0.w = fmaf(w, v0.w, o0.w);
            o1.x = fmaf(w, v1.x, o1.x); o1.y = fmaf(w, v1.y, o1.y);
            o1.z = fmaf(w, v1.z, o1.z); o1.w = fmaf(w, v1.w, o1.w);
        }
    }

    // stage S_prev (32x32) into tile LDS
    __syncthreads();
    ((float4*)tile)[tid] = ((const float4*)(rec + (size_t)chunk * 1024))[tid];
    __syncthreads();
    if (!active) return;

    const float er = expf(dec);
    const float inv1mr = 1.0f / (1.0f - er);
    const float lrs = (1.0f - expf(dec * (float)CHUNKN)) * inv1mr;
    const float rowsum = (1.0f - expf(dec * (float)(i + 1))) * inv1mr;
    const float scale_i = sqrtf(rowsum);
    const float inv_scale = 1.0f / scale_i;
    const float f_i = expf(dec * (float)i) * inv_scale;
    const float inner_scale = fmaxf(absacc * f_i, 1.0f);
    const float sgp = sig[chunk];
    const float all_scale = fmaxf(inner_scale, sgp);
    o0.x *= f_i; o0.y *= f_i; o0.z *= f_i; o0.w *= f_i;
    o1.x *= f_i; o1.y *= f_i; o1.z *= f_i; o1.w *= f_i;

    // cross term: o[cols] += sum_k q[k]*qdec * S[k][cols]
    const float qdec = expf(dec * (float)(i + 1)) * lrs * inv_scale;
    #pragma unroll
    for (int sc = 0; sc < 4; ++sc) {
        int srcl = (lane & 60) | sc;
        float qs[8];
        qs[0] = __shfl(q0.x, srcl); qs[1] = __shfl(q0.y, srcl);
        qs[2] = __shfl(q0.z, srcl); qs[3] = __shfl(q0.w, srcl);
        qs[4] = __shfl(q1.x, srcl); qs[5] = __shfl(q1.y, srcl);
        qs[6] = __shfl(q1.z, srcl); qs[7] = __shfl(q1.w, srcl);
        #pragma unroll
        for (int r = 0; r < 8; ++r) {
            float coef = qs[r] * qdec;
            const float4* srow = (const float4*)(tile + (sc * 8 + r) * 32 + c * 8);
            float4 s0 = srow[0], s1 = srow[1];
            o0.x = fmaf(coef, s0.x, o0.x); o0.y = fmaf(coef, s0.y, o0.y);
            o0.z = fmaf(coef, s0.z, o0.z); o0.w = fmaf(coef, s0.w, o0.w);
            o1.x = fmaf(coef, s1.x, o1.x); o1.y = fmaf(coef, s1.y, o1.y);
            o1.z = fmaf(coef, s1.z, o1.z); o1.w = fmaf(coef, s1.w, o1.w);
        }
    }

    const float inv_all = 1.0f / all_scale;
    o0.x *= inv_all; o0.y *= inv_all; o0.z *= inv_all; o0.w *= inv_all;
    o1.x *= inv_all; o1.y *= inv_all; o1.z *= inv_all; o1.w *= inv_all;
    float ms = o0.x * o0.x + o0.y * o0.y + o0.z * o0.z + o0.w * o0.w +
               o1.x * o1.x + o1.y * o1.y + o1.z * o1.z + o1.w * o1.w;
    ms += __shfl_xor(ms, 1);
    ms += __shfl_xor(ms, 2);
    const float rn = rsqrtf(ms * (1.0f / 32.0f) + 1e-6f);
    const int tg = n * CHUNKN + i;
    const float4* gp = (const float4*)(g + ((size_t)b * TLEN + tg) * 256 + h * KD + c * 8);
    float4* ap = (float4*)(abuf + ((size_t)b * TLEN + tg) * 256 + h * KD + c * 8);
    float4 gv0 = gp[0], gv1 = gp[1];
    float4 w0, w1;
    w0.x = (gv0.x / (1.0f + expf(-gv0.x))) * (o0.x * rn);
    w0.y = (gv0.y / (1.0f + expf(-gv0.y))) * (o0.y * rn);
    w0.z = (gv0.z / (1.0f + expf(-gv0.z))) * (o0.z * rn);
    w0.w = (gv0.w / (1.0f + expf(-gv0.w))) * (o0.w * rn);
    w1.x = (gv1.x / (1.0f + expf(-gv1.x))) * (o1.x * rn);
    w1.y = (gv1.y / (1.0f + expf(-gv1.y))) * (o1.y * rn);
    w1.z = (gv1.z / (1.0f + expf(-gv1.z))) * (o1.z * rn);
    w1.w = (gv1.w / (1.0f + expf(-gv1.w))) * (o1.w * rn);
    ap[0] = w0; ap[1] = w1;
}

// ---------------------------------------------------------------- tiny MHA (seq len 4)
__global__ __launch_bounds__(256) void mha_attn(const float* __restrict__ qh,
                                                const float* __restrict__ kh,
                                                const float* __restrict__ vh,
                                                float* __restrict__ oh) {
    int gidx = blockIdx.x * 256 + threadIdx.x;
    if (gidx >= 2 * TLEN * NHEADS * 4) return;
    int i = gidx & 3;
    int h = (gidx >> 2) & 7;
    int rest = gidx >> 5;  // b*2000 + t
    int t = rest % TLEN;
    int b = rest / TLEN;
    size_t rows[4];
    #pragma unroll
    for (int c = 0; c < 4; ++c) rows[c] = ((size_t)(b * 4 + c) * TLEN + t);
    const float4* q4 = (const float4*)(qh + rows[i] * 256 + h * 32);
    float4 q[8];
    #pragma unroll
    for (int r = 0; r < 8; ++r) q[r] = q4[r];
    float s[4];
    #pragma unroll
    for (int j = 0; j < 4; ++j) {
        const float4* k4 = (const float4*)(kh + rows[j] * 256 + h * 32);
        float a0 = 0, a1 = 0, a2 = 0, a3 = 0;
        #pragma unroll
        for (int r = 0; r < 8; ++r) {
            float4 kk = k4[r];
            a0 = fmaf(q[r].x, kk.x, a0);
            a1 = fmaf(q[r].y, kk.y, a1);
            a2 = fmaf(q[r].z, kk.z, a2);
            a3 = fmaf(q[r].w, kk.w, a3);
        }
        s[j] = (a0 + a1) + (a2 + a3);
    }
    float m = fmaxf(fmaxf(s[0], s[1]), fmaxf(s[2], s[3]));
    float p[4], den = 0.f;
    #pragma unroll
    for (int j = 0; j < 4; ++j) { p[j] = expf(s[j] - m); den += p[j]; }
    float inv = 1.0f / den;
    float4 o[8];
    #pragma unroll
    for (int r = 0; r < 8; ++r) o[r] = make_float4(0.f, 0.f, 0.f, 0.f);
    #pragma unroll
    for (int j = 0; j < 4; ++j) {
        float wj = p[j] * inv;
        const float4* v4 = (const float4*)(vh + rows[j] * 256 + h * 32);
        #pragma unroll
        for (int r = 0; r < 8; ++r) {
            float4 vv = v4[r];
            o[r].x = fmaf(wj, vv.x, o[r].x);
            o[r].y = fmaf(wj, vv.y, o[r].y);
            o[r].z = fmaf(wj, vv.z, o[r].z);
            o[r].w = fmaf(wj, vv.w, o[r].w);
        }
    }
    float4* d4 = (float4*)(oh + rows[i] * 256 + h * 32);
    #pragma unroll
    for (int r = 0; r < 8; ++r) d4[r] = o[r];
}

// ---------------------------------------------------------------- launch
extern "C" void kernel_launch(void* const* d_in, const int* in_sizes, int n_in,
                              void* d_out, int out_size, void* d_ws, size_t ws_size,
                              hipStream_t stream) {
    (void)in_sizes; (void)n_in; (void)out_size; (void)ws_size;
    const float* x    = (const float*)d_in[0];
    const float* ln1g = (const float*)d_in[1];
    const float* ln1b = (const float*)d_in[2];
    const float* ln2g = (const float*)d_in[3];
    const float* ln2b = (const float*)d_in[4];
    const float* qw   = (const float*)d_in[5];
    const float* kw   = (const float*)d_in[6];
    const float* vw   = (const float*)d_in[7];
    const float* gw   = (const float*)d_in[8];
    const float* ow   = (const float*)d_in[9];
    const float* in_w = (const float*)d_in[10];
    const float* in_b = (const float*)d_in[11];
    const float* outw = (const float*)d_in[12];
    const float* outb = (const float*)d_in[13];
    float* out = (float*)d_out;
    float* ws = (float*)d_ws;

    // workspace layout (floats)
    constexpr size_t O_SIN = 0;
    constexpr size_t O_COS = O_SIN + (size_t)TLEN * KD;           // 64000
    constexpr size_t O_A   = O_COS + (size_t)TLEN * KD;           // xn / kvp / abuf / q-hat
    constexpr size_t O_B   = O_A + 4096000;                       // qr / x2
    constexpr size_t O_C   = O_B + 4096000;                       // kr / yn / attnout
    constexpr size_t O_D   = O_C + 4096000;                       // v  / k-hat
    constexpr size_t O_E   = O_D + 4096000;                       // g  / v-hat
    constexpr size_t O_REC = O_E + 4096000;                       // 262144
    constexpr size_t O_SIG = O_REC + 262144;                      // 256

    float* sinT = ws + O_SIN;
    float* cosT = ws + O_COS;
    float* bufA = ws + O_A;
    float* bufB = ws + O_B;
    float* bufC = ws + O_C;
    float* bufD = ws + O_D;
    float* bufE = ws + O_E;
    float* recb = ws + O_REC;
    float* sigb = ws + O_SIG;

    // 0) rotary tables
    tab_kernel<<<250, 256, 0, stream>>>(sinT, cosT);
    // 1) LN1: x -> xn (bufA)
    ln_kernel<<<MROWS / 4, 256, 0, stream>>>(x, ln1g, ln1b, bufA, MROWS);
    // 2) projections: xn @ [qw kw vw gw].T -> qr(B) kr(C) v(D) g(E)
    gemm_fused<0><<<dim3(16, MROWS / 64), 256, 0, stream>>>(
        bufA, qw, kw, vw, gw, sinT, cosT, nullptr, nullptr, bufB, bufC, bufD, bufE);
    // 3) kv partials -> bufA (xn dead)
    kvp_kernel<<<1024, 256, 0, stream>>>(bufC, bufD, bufA);
    // 4) cross-chunk scan -> rec, sig
    scan_kernel<<<64, 256, 0, stream>>>(bufA, recb, sigb);
    // 5) retention core -> abuf (bufA; kvp dead)
    ret_core2<<<2048, 256, 0, stream>>>(bufB, bufC, bufD, bufE, recb, sigb, bufA);
    // 6) out-proj + residual: x + abuf @ ow.T -> x2 (bufB)
    gemm_fused<1><<<dim3(4, MROWS / 64), 256, 0, stream>>>(
        bufA, ow, nullptr, nullptr, nullptr, nullptr, nullptr, nullptr, x,
        bufB, nullptr, nullptr, nullptr);
    // 7) LN2: x2 -> yn (bufC)
    ln_kernel<<<MROWS / 4, 256, 0, stream>>>(bufB, ln2g, ln2b, bufC, MROWS);
    // 8) qkv: yn @ in_w.T + in_b -> qhat(A) khat(D) vhat(E)
    gemm_fused<2><<<dim3(12, MROWS / 64), 256, 0, stream>>>(
        bufC, in_w, nullptr, nullptr, nullptr, nullptr, nullptr, in_b, nullptr,
        bufA, bufD, bufE, nullptr);
    // 9) tiny attention -> attnout (bufC)
    mha_attn<<<500, 256, 0, stream>>>(bufA, bufD, bufE, bufC);
    // 10) final: x2 + attnout @ out_w.T + out_b -> d_out
    gemm_fused<3><<<dim3(4, MROWS / 64), 256, 0, stream>>>(
        bufC, outw, nullptr, nullptr, nullptr, nullptr, nullptr, outb, bufB,
        out, nullptr, nullptr, nullptr);
}

// Round 6
// 377.631 us; speedup vs baseline: 2.2045x; 1.4633x over previous
//
#include <hip/hip_runtime.h>
#include <math.h>

#define TLEN 2000
#define NSEQ 8       // B*C
#define NHEADS 8
#define KD 32
#define CHUNKN 500
#define NCHUNK 4
#define MROWS 16000  // NSEQ*TLEN
#define SCALING 0.1767766952966369f

typedef float f32x4 __attribute__((ext_vector_type(4)));
typedef short s16x8 __attribute__((ext_vector_type(8)));
typedef unsigned short u16x8 __attribute__((ext_vector_type(8)));
typedef unsigned short u16x4 __attribute__((ext_vector_type(4)));

__device__ __forceinline__ unsigned short f2bf(float f) {
    unsigned int u = __float_as_uint(f);
    unsigned int r = (u + 0x7FFFu + ((u >> 16) & 1u)) >> 16;
    return (unsigned short)r;
}
__device__ __forceinline__ float bf2f(unsigned short h) {
    return __uint_as_float(((unsigned int)h) << 16);
}

// ---------------------------------------------------------------- tables (16 angles)
__global__ __launch_bounds__(256) void tab_kernel(float* __restrict__ sinT,
                                                  float* __restrict__ cosT) {
    int idx = blockIdx.x * 256 + threadIdx.x;
    if (idx >= TLEN * 16) return;
    int t = idx >> 4, a = idx & 15;
    float ang = powf(10000.0f, -(float)a / 15.0f);
    float th = (float)t * ang;
    sinT[idx] = sinf(th);
    cosT[idx] = cosf(th);
}

// ---------------------------------------------------------------- weight cast fp32 -> bf16 concat
__global__ __launch_bounds__(256) void wcast_kernel(
    const float* __restrict__ qw, const float* __restrict__ kw,
    const float* __restrict__ vw, const float* __restrict__ gw,
    const float* __restrict__ ow, const float* __restrict__ inw,
    const float* __restrict__ outw, unsigned short* __restrict__ W) {
    int i = blockIdx.x * 1024 + threadIdx.x * 4;
    const float* src; int off;
    if (i < 65536)       { src = qw;   off = i; }
    else if (i < 131072) { src = kw;   off = i - 65536; }
    else if (i < 196608) { src = vw;   off = i - 131072; }
    else if (i < 262144) { src = gw;   off = i - 196608; }
    else if (i < 327680) { src = ow;   off = i - 262144; }
    else if (i < 524288) { src = inw;  off = i - 327680; }
    else                 { src = outw; off = i - 524288; }
    float4 v = *(const float4*)(src + off);
    u16x4 o;
    o[0] = f2bf(v.x); o[1] = f2bf(v.y); o[2] = f2bf(v.z); o[3] = f2bf(v.w);
    *(u16x4*)(W + i) = o;
}

// ---------------------------------------------------------------- layernorm -> bf16 hi/lo
__global__ __launch_bounds__(256) void ln_kernel(const float* __restrict__ x,
                                                 const float* __restrict__ gam,
                                                 const float* __restrict__ bet,
                                                 unsigned short* __restrict__ H,
                                                 unsigned short* __restrict__ L,
                                                 int rows) {
    int wid = threadIdx.x >> 6, lane = threadIdx.x & 63;
    int row = blockIdx.x * 4 + wid;
    if (row >= rows) return;
    const float* xr = x + (size_t)row * 256;
    float4 v = *(const float4*)(xr + lane * 4);
    float s = v.x + v.y + v.z + v.w;
    #pragma unroll
    for (int o = 32; o; o >>= 1) s += __shfl_xor(s, o);
    float mu = s * (1.0f / 256.0f);
    float dx = v.x - mu, dy = v.y - mu, dz = v.z - mu, dw = v.w - mu;
    float ss = dx * dx + dy * dy + dz * dz + dw * dw;
    #pragma unroll
    for (int o = 32; o; o >>= 1) ss += __shfl_xor(ss, o);
    float rstd = rsqrtf(ss * (1.0f / 256.0f) + 1e-5f);
    float4 g4 = *(const float4*)(gam + lane * 4);
    float4 b4 = *(const float4*)(bet + lane * 4);
    float ov[4];
    ov[0] = dx * rstd * g4.x + b4.x;
    ov[1] = dy * rstd * g4.y + b4.y;
    ov[2] = dz * rstd * g4.z + b4.z;
    ov[3] = dw * rstd * g4.w + b4.w;
    u16x4 hv, lv;
    #pragma unroll
    for (int j = 0; j < 4; ++j) {
        hv[j] = f2bf(ov[j]);
        lv[j] = f2bf(ov[j] - bf2f(hv[j]));
    }
    *(u16x4*)(H + (size_t)row * 256 + lane * 4) = hv;
    *(u16x4*)(L + (size_t)row * 256 + lane * 4) = lv;
}

// ---------------------------------------------------------------- MFMA GEMM  y = A @ W.T, K=256
// A given as bf16 hi/lo pair (exact fp32 reconstruction); W bf16.
// MODE 0: proj -> qr/kr (rotary, k*SCALING) head-layout, v head-layout, g row-layout
// MODE 1: out = resid + acc
// MODE 2: qkv + bias, q*SCALING, split 3 dsts
// MODE 3: out = resid + acc + bias
template <int MODE>
__global__ __launch_bounds__(256, 2) void gemm_mfma(
    const unsigned short* __restrict__ AH, const unsigned short* __restrict__ AL,
    const unsigned short* __restrict__ Wc, const float* __restrict__ sinT,
    const float* __restrict__ cosT, const float* __restrict__ bias,
    const float* __restrict__ resid, float* __restrict__ D0,
    float* __restrict__ D1, float* __restrict__ D2, float* __restrict__ D3) {
    __shared__ unsigned short Ah[128][72];
    __shared__ unsigned short Al[128][72];
    __shared__ unsigned short Bt[128][72];
    const int tid = threadIdx.x;
    const int m0 = blockIdx.y * 128, n0 = blockIdx.x * 128;
    size_t wbase;
    if constexpr (MODE == 0)      wbase = (size_t)(n0 >> 8) * 65536 + (size_t)(n0 & 255) * 256;
    else if constexpr (MODE == 1) wbase = 262144 + (size_t)n0 * 256;
    else if constexpr (MODE == 2) wbase = 327680 + (size_t)n0 * 256;
    else                          wbase = 524288 + (size_t)n0 * 256;

    const int wid = tid >> 6, lane = tid & 63;
    const int wm = wid >> 1, wn = wid & 1;
    const int lr = lane & 15, lk = lane >> 4;
    const int str = tid >> 3;         // staging row base (0..31)
    const int stc = (tid & 7) * 8;    // staging col

    f32x4 acc[4][4] = {};

    for (int kt = 0; kt < 256; kt += 64) {
        if (kt) __syncthreads();
        #pragma unroll
        for (int it = 0; it < 4; ++it) {
            int r = it * 32 + str;
            u16x8 va = *(const u16x8*)(AH + (size_t)(m0 + r) * 256 + kt + stc);
            u16x8 vl = *(const u16x8*)(AL + (size_t)(m0 + r) * 256 + kt + stc);
            u16x8 vw = *(const u16x8*)(Wc + wbase + (size_t)r * 256 + kt + stc);
            *(u16x8*)(&Ah[r][stc]) = va;
            *(u16x8*)(&Al[r][stc]) = vl;
            *(u16x8*)(&Bt[r][stc]) = vw;
        }
        __syncthreads();
        #pragma unroll
        for (int ks = 0; ks < 2; ++ks) {
            const int k0 = ks * 32 + lk * 8;
            s16x8 af[4], alf[4], bf[4];
            #pragma unroll
            for (int f = 0; f < 4; ++f) {
                af[f]  = *(const s16x8*)(&Ah[wm * 64 + f * 16 + lr][k0]);
                alf[f] = *(const s16x8*)(&Al[wm * 64 + f * 16 + lr][k0]);
                bf[f]  = *(const s16x8*)(&Bt[wn * 64 + f * 16 + lr][k0]);
            }
            #pragma unroll
            for (int fm = 0; fm < 4; ++fm)
                #pragma unroll
                for (int fn = 0; fn < 4; ++fn) {
                    acc[fm][fn] = __builtin_amdgcn_mfma_f32_16x16x32_bf16(af[fm], bf[fn], acc[fm][fn], 0, 0, 0);
                    acc[fm][fn] = __builtin_amdgcn_mfma_f32_16x16x32_bf16(alf[fm], bf[fn], acc[fm][fn], 0, 0, 0);
                }
        }
    }

    // epilogue: elem (fm,fn,r): row = m0+wm*64+fm*16+lk*4+r, col = n0+wn*64+fn*16+lr
    if constexpr (MODE == 0) {
        const int w = n0 >> 8;  // block-uniform
        const float sc = (w == 1) ? SCALING : 1.0f;
        #pragma unroll
        for (int fn = 0; fn < 4; ++fn) {
            const int c = n0 + wn * 64 + fn * 16 + lr;
            const int cb = c & 255, h = cb >> 5, d0 = cb & 31;
            #pragma unroll
            for (int fm = 0; fm < 4; ++fm)
                #pragma unroll
                for (int r = 0; r < 4; ++r) {
                    const int i = m0 + wm * 64 + fm * 16 + lk * 4 + r;
                    const int b = i / TLEN, t = i - b * TLEN;
                    float v = acc[fm][fn][r] * sc;
                    if (w <= 1) {
                        float oth = __shfl_xor(v, 1);
                        float cs = cosT[t * 16 + (d0 >> 1)];
                        float sn = sinT[t * 16 + (d0 >> 1)];
                        float outv = (d0 & 1) ? fmaf(v, cs, oth * sn) : fmaf(v, cs, -(oth * sn));
                        ((w == 0) ? D0 : D1)[((size_t)(b * NHEADS + h) * TLEN + t) * KD + d0] = outv;
                    } else if (w == 2) {
                        D2[((size_t)(b * NHEADS + h) * TLEN + t) * KD + d0] = v;
                    } else {
                        D3[(size_t)i * 256 + cb] = v;
                    }
                }
        }
    } else if constexpr (MODE == 1) {
        #pragma unroll
        for (int fn = 0; fn < 4; ++fn) {
            const int c = n0 + wn * 64 + fn * 16 + lr;
            #pragma unroll
            for (int fm = 0; fm < 4; ++fm)
                #pragma unroll
                for (int r = 0; r < 4; ++r) {
                    const int i = m0 + wm * 64 + fm * 16 + lk * 4 + r;
                    D0[(size_t)i * 256 + c] = resid[(size_t)i * 256 + c] + acc[fm][fn][r];
                }
        }
    } else if constexpr (MODE == 2) {
        const int w = n0 >> 8;  // block-uniform
        const float qs = (w == 0) ? SCALING : 1.0f;
        float* Dsel = (w == 0) ? D0 : (w == 1) ? D1 : D2;
        #pragma unroll
        for (int fn = 0; fn < 4; ++fn) {
            const int c = n0 + wn * 64 + fn * 16 + lr;
            const int cb = c & 255;
            const float bv = bias[c];
            #pragma unroll
            for (int fm = 0; fm < 4; ++fm)
                #pragma unroll
                for (int r = 0; r < 4; ++r) {
                    const int i = m0 + wm * 64 + fm * 16 + lk * 4 + r;
                    Dsel[(size_t)i * 256 + cb] = (acc[fm][fn][r] + bv) * qs;
                }
        }
    } else {
        #pragma unroll
        for (int fn = 0; fn < 4; ++fn) {
            const int c = n0 + wn * 64 + fn * 16 + lr;
            const float bv = bias[c];
            #pragma unroll
            for (int fm = 0; fm < 4; ++fm)
                #pragma unroll
                for (int r = 0; r < 4; ++r) {
                    const int i = m0 + wm * 64 + fm * 16 + lk * 4 + r;
                    D0[(size_t)i * 256 + c] = resid[(size_t)i * 256 + c] + acc[fm][fn][r] + bv;
                }
        }
    }
}

// ---------------------------------------------------------------- kv partials (2 j-subchunks)
__global__ __launch_bounds__(256) void kvp_kernel(const float* __restrict__ kr,
                                                  const float* __restrict__ v,
                                                  float* __restrict__ kvp) {
    int blk = blockIdx.x;
    int sub = blk & 1, rest = blk >> 1;
    int b = rest >> 5, n = (rest >> 3) & 3, h = rest & 7;
    int tid = threadIdx.x;
    int k = tid >> 3, d0 = (tid & 7) * 4;
    float dec = logf(1.0f - exp2f(-5.0f - (float)h));
    float lrs = (1.0f - expf(dec * (float)CHUNKN)) / (1.0f - expf(dec));
    float invl = 1.0f / lrs;
    const float* krb = kr + ((size_t)(b * NHEADS + h) * TLEN + n * CHUNKN) * KD;
    const float* vb = v + ((size_t)(b * NHEADS + h) * TLEN + n * CHUNKN) * KD;
    float a0 = 0, a1 = 0, a2 = 0, a3 = 0;
    int j0 = sub * 250;
    for (int j = j0; j < j0 + 250; ++j) {
        float kj = krb[(size_t)j * KD + k];
        float vd = expf(dec * (float)(CHUNKN - 1 - j)) * invl;
        float w = kj * vd;
        float4 vv = *(const float4*)(vb + (size_t)j * KD + d0);
        a0 = fmaf(w, vv.x, a0); a1 = fmaf(w, vv.y, a1);
        a2 = fmaf(w, vv.z, a2); a3 = fmaf(w, vv.w, a3);
    }
    float* dst = kvp + ((size_t)rest * 2 + sub) * 1024 + k * 32 + d0;
    dst[0] = a0; dst[1] = a1; dst[2] = a2; dst[3] = a3;
}

// ---------------------------------------------------------------- cross-chunk scan
__global__ __launch_bounds__(256) void scan_kernel(const float* __restrict__ kvp,
                                                   float* __restrict__ rec,
                                                   float* __restrict__ sig) {
    __shared__ float cs[32];
    __shared__ float ssig;
    int blk = blockIdx.x;
    int b = blk >> 3, h = blk & 7;
    int tid = threadIdx.x;
    float dec = logf(1.0f - exp2f(-5.0f - (float)h));
    float cd = expf(dec * (float)CHUNKN);
    float S0 = 0, S1 = 0, S2 = 0, S3 = 0;
    float sigma = 1.0f;
    for (int n = 0; n < NCHUNK; ++n) {
        int rest = b * 32 + n * 8 + h;
        size_t rbase = (size_t)rest * 1024;
        size_t pbase = (size_t)rest * 2048;
        rec[rbase + tid] = S0;
        rec[rbase + tid + 256] = S1;
        rec[rbase + tid + 512] = S2;
        rec[rbase + tid + 768] = S3;
        if (tid == 0) sig[rest] = sigma;
        float k0 = 0, k1 = 0, k2 = 0, k3 = 0;
        #pragma unroll
        for (int s = 0; s < 2; ++s) {
            k0 += kvp[pbase + s * 1024 + tid];
            k1 += kvp[pbase + s * 1024 + tid + 256];
            k2 += kvp[pbase + s * 1024 + tid + 512];
            k3 += kvp[pbase + s * 1024 + tid + 768];
        }
        S0 = S0 * cd + k0;
        S1 = S1 * cd + k1;
        S2 = S2 * cd + k2;
        S3 = S3 * cd + k3;
        if (tid < 32) cs[tid] = 0.f;
        __syncthreads();
        float part = fabsf(S0) + fabsf(S1) + fabsf(S2) + fabsf(S3);
        atomicAdd(&cs[tid & 31], part);
        __syncthreads();
        if (tid == 0) {
            float m = cs[0];
            for (int d = 1; d < 32; ++d) m = fmaxf(m, cs[d]);
            ssig = fmaxf(m, 1.0f);
        }
        __syncthreads();
        sigma = ssig;
    }
}

// ---------------------------------------------------------------- retention core (epilogue -> bf16 hi/lo)
__global__ __launch_bounds__(256, 8) void ret_core2(
    const float* __restrict__ qr, const float* __restrict__ kr,
    const float* __restrict__ v, const float* __restrict__ g,
    const float* __restrict__ rec, const float* __restrict__ sig,
    unsigned short* __restrict__ ABH, unsigned short* __restrict__ ABL) {
    __shared__ float tile[64 * 68];
    const int u = 7 - (int)(blockIdx.x >> 8);
    const int chunk = blockIdx.x & 255;
    const int b = chunk >> 5, n = (chunk >> 3) & 3, h = chunk & 7;
    const int tid = threadIdx.x;
    const int c = tid & 3, il = tid >> 2;
    const int i = u * 64 + il;
    const bool active = (i < CHUNKN);
    const int lane = tid & 63;
    const int wid = tid >> 6;
    const int iwmax = min(u * 64 + wid * 16 + 15, CHUNKN - 1);
    const float dec = logf(1.0f - exp2f(-5.0f - (float)h));
    const float ndec = -dec;
    const size_t cbase = ((size_t)(b * NHEADS + h) * TLEN + n * CHUNKN) * KD;

    float4 q0 = make_float4(0.f, 0.f, 0.f, 0.f), q1 = q0;
    if (active) {
        const float4* qp = (const float4*)(qr + cbase + (size_t)i * KD + c * 8);
        q0 = qp[0]; q1 = qp[1];
    }
    float4 o0 = make_float4(0.f, 0.f, 0.f, 0.f), o1 = o0;
    float absacc = 0.f;

    for (int jt = 0; jt <= u; ++jt) {
        if (jt) __syncthreads();
        {
            int jg = jt * 64 + il;
            float4 kx0 = make_float4(0.f, 0.f, 0.f, 0.f), kx1 = kx0, vx0 = kx0, vx1 = kx0;
            if (jg < CHUNKN) {
                const float4* kp = (const float4*)(kr + cbase + (size_t)jg * KD + c * 8);
                const float4* vp = (const float4*)(v + cbase + (size_t)jg * KD + c * 8);
                float ej = expf(ndec * (float)jg);
                kx0 = kp[0]; kx1 = kp[1];
                kx0.x *= ej; kx0.y *= ej; kx0.z *= ej; kx0.w *= ej;
                kx1.x *= ej; kx1.y *= ej; kx1.z *= ej; kx1.w *= ej;
                vx0 = vp[0]; vx1 = vp[1];
            }
            float4* tw = (float4*)(tile + il * 68);
            tw[c * 2] = kx0; tw[c * 2 + 1] = kx1;
            tw[8 + c * 2] = vx0; tw[8 + c * 2 + 1] = vx1;
        }
        __syncthreads();
        const int jcnt = min(63, iwmax - jt * 64);
        const int jbase = jt * 64;
        for (int jl = 0; jl <= jcnt; ++jl) {
            const float4* tp = (const float4*)(tile + jl * 68);
            float4 k0 = tp[c * 2], k1 = tp[c * 2 + 1];
            float4 v0 = tp[8 + c * 2], v1 = tp[8 + c * 2 + 1];
            float da = fmaf(q0.x, k0.x, q0.y * k0.y);
            float db = fmaf(q0.z, k0.z, q0.w * k0.w);
            float dcc = fmaf(q1.x, k1.x, q1.y * k1.y);
            float dd = fmaf(q1.z, k1.z, q1.w * k1.w);
            float d = (da + db) + (dcc + dd);
            d += __shfl_xor(d, 1);
            d += __shfl_xor(d, 2);
            float w = ((jbase + jl) <= i) ? d : 0.f;
            absacc += fabsf(w);
            o0.x = fmaf(w, v0.x, o0.x); o0.y = fmaf(w, v0.y, o0.y);
            o0.z = fmaf(w, v0.z, o0.z); o0.w = fmaf(w, v0.w, o0.w);
            o1.x = fmaf(w, v1.x, o1.x); o1.y = fmaf(w, v1.y, o1.y);
            o1.z = fmaf(w, v1.z, o1.z); o1.w = fmaf(w, v1.w, o1.w);
        }
    }

    __syncthreads();
    ((float4*)tile)[tid] = ((const float4*)(rec + (size_t)chunk * 1024))[tid];
    __syncthreads();
    if (!active) return;

    const float er = expf(dec);
    const float inv1mr = 1.0f / (1.0f - er);
    const float lrs = (1.0f - expf(dec * (float)CHUNKN)) * inv1mr;
    const float rowsum = (1.0f - expf(dec * (float)(i + 1))) * inv1mr;
    const float scale_i = sqrtf(rowsum);
    const float inv_scale = 1.0f / scale_i;
    const float f_i = expf(dec * (float)i) * inv_scale;
    const float inner_scale = fmaxf(absacc * f_i, 1.0f);
    const float sgp = sig[chunk];
    const float all_scale = fmaxf(inner_scale, sgp);
    o0.x *= f_i; o0.y *= f_i; o0.z *= f_i; o0.w *= f_i;
    o1.x *= f_i; o1.y *= f_i; o1.z *= f_i; o1.w *= f_i;

    const float qdec = expf(dec * (float)(i + 1)) * lrs * inv_scale;
    #pragma unroll
    for (int sc = 0; sc < 4; ++sc) {
        int srcl = (lane & 60) | sc;
        float qs[8];
        qs[0] = __shfl(q0.x, srcl); qs[1] = __shfl(q0.y, srcl);
        qs[2] = __shfl(q0.z, srcl); qs[3] = __shfl(q0.w, srcl);
        qs[4] = __shfl(q1.x, srcl); qs[5] = __shfl(q1.y, srcl);
        qs[6] = __shfl(q1.z, srcl); qs[7] = __shfl(q1.w, srcl);
        #pragma unroll
        for (int r = 0; r < 8; ++r) {
            float coef = qs[r] * qdec;
            const float4* srow = (const float4*)(tile + (sc * 8 + r) * 32 + c * 8);
            float4 s0 = srow[0], s1 = srow[1];
            o0.x = fmaf(coef, s0.x, o0.x); o0.y = fmaf(coef, s0.y, o0.y);
            o0.z = fmaf(coef, s0.z, o0.z); o0.w = fmaf(coef, s0.w, o0.w);
            o1.x = fmaf(coef, s1.x, o1.x); o1.y = fmaf(coef, s1.y, o1.y);
            o1.z = fmaf(coef, s1.z, o1.z); o1.w = fmaf(coef, s1.w, o1.w);
        }
    }

    const float inv_all = 1.0f / all_scale;
    o0.x *= inv_all; o0.y *= inv_all; o0.z *= inv_all; o0.w *= inv_all;
    o1.x *= inv_all; o1.y *= inv_all; o1.z *= inv_all; o1.w *= inv_all;
    float ms = o0.x * o0.x + o0.y * o0.y + o0.z * o0.z + o0.w * o0.w +
               o1.x * o1.x + o1.y * o1.y + o1.z * o1.z + o1.w * o1.w;
    ms += __shfl_xor(ms, 1);
    ms += __shfl_xor(ms, 2);
    const float rn = rsqrtf(ms * (1.0f / 32.0f) + 1e-6f);
    const int tg = n * CHUNKN + i;
    const float4* gp = (const float4*)(g + ((size_t)b * TLEN + tg) * 256 + h * KD + c * 8);
    float4 gv0 = gp[0], gv1 = gp[1];
    float vals[8];
    vals[0] = (gv0.x / (1.0f + expf(-gv0.x))) * (o0.x * rn);
    vals[1] = (gv0.y / (1.0f + expf(-gv0.y))) * (o0.y * rn);
    vals[2] = (gv0.z / (1.0f + expf(-gv0.z))) * (o0.z * rn);
    vals[3] = (gv0.w / (1.0f + expf(-gv0.w))) * (o0.w * rn);
    vals[4] = (gv1.x / (1.0f + expf(-gv1.x))) * (o1.x * rn);
    vals[5] = (gv1.y / (1.0f + expf(-gv1.y))) * (o1.y * rn);
    vals[6] = (gv1.z / (1.0f + expf(-gv1.z))) * (o1.z * rn);
    vals[7] = (gv1.w / (1.0f + expf(-gv1.w))) * (o1.w * rn);
    u16x8 hv, lv;
    #pragma unroll
    for (int j = 0; j < 8; ++j) {
        hv[j] = f2bf(vals[j]);
        lv[j] = f2bf(vals[j] - bf2f(hv[j]));
    }
    size_t off = ((size_t)b * TLEN + tg) * 256 + h * KD + c * 8;
    *(u16x8*)(ABH + off) = hv;
    *(u16x8*)(ABL + off) = lv;
}

// ---------------------------------------------------------------- tiny MHA (seq len 4) -> bf16 hi/lo
__global__ __launch_bounds__(256) void mha_attn(const float* __restrict__ qh,
                                                const float* __restrict__ kh,
                                                const float* __restrict__ vh,
                                                unsigned short* __restrict__ OH,
                                                unsigned short* __restrict__ OL) {
    int gidx = blockIdx.x * 256 + threadIdx.x;
    if (gidx >= 2 * TLEN * NHEADS * 4) return;
    int i = gidx & 3;
    int h = (gidx >> 2) & 7;
    int rest = gidx >> 5;  // b*2000 + t
    int t = rest % TLEN;
    int b = rest / TLEN;
    size_t rows[4];
    #pragma unroll
    for (int c = 0; c < 4; ++c) rows[c] = ((size_t)(b * 4 + c) * TLEN + t);
    const float4* q4 = (const float4*)(qh + rows[i] * 256 + h * 32);
    float4 q[8];
    #pragma unroll
    for (int r = 0; r < 8; ++r) q[r] = q4[r];
    float s[4];
    #pragma unroll
    for (int j = 0; j < 4; ++j) {
        const float4* k4 = (const float4*)(kh + rows[j] * 256 + h * 32);
        float a0 = 0, a1 = 0, a2 = 0, a3 = 0;
        #pragma unroll
        for (int r = 0; r < 8; ++r) {
            float4 kk = k4[r];
            a0 = fmaf(q[r].x, kk.x, a0);
            a1 = fmaf(q[r].y, kk.y, a1);
            a2 = fmaf(q[r].z, kk.z, a2);
            a3 = fmaf(q[r].w, kk.w, a3);
        }
        s[j] = (a0 + a1) + (a2 + a3);
    }
    float m = fmaxf(fmaxf(s[0], s[1]), fmaxf(s[2], s[3]));
    float p[4], den = 0.f;
    #pragma unroll
    for (int j = 0; j < 4; ++j) { p[j] = expf(s[j] - m); den += p[j]; }
    float inv = 1.0f / den;
    float4 o[8];
    #pragma unroll
    for (int r = 0; r < 8; ++r) o[r] = make_float4(0.f, 0.f, 0.f, 0.f);
    #pragma unroll
    for (int j = 0; j < 4; ++j) {
        float wj = p[j] * inv;
        const float4* v4 = (const float4*)(vh + rows[j] * 256 + h * 32);
        #pragma unroll
        for (int r = 0; r < 8; ++r) {
            float4 vv = v4[r];
            o[r].x = fmaf(wj, vv.x, o[r].x);
            o[r].y = fmaf(wj, vv.y, o[r].y);
            o[r].z = fmaf(wj, vv.z, o[r].z);
            o[r].w = fmaf(wj, vv.w, o[r].w);
        }
    }
    #pragma unroll
    for (int r = 0; r < 8; ++r) {
        float vv[4] = {o[r].x, o[r].y, o[r].z, o[r].w};
        u16x4 hv, lv;
        #pragma unroll
        for (int j = 0; j < 4; ++j) {
            hv[j] = f2bf(vv[j]);
            lv[j] = f2bf(vv[j] - bf2f(hv[j]));
        }
        *(u16x4*)(OH + rows[i] * 256 + h * 32 + r * 4) = hv;
        *(u16x4*)(OL + rows[i] * 256 + h * 32 + r * 4) = lv;
    }
}

// ---------------------------------------------------------------- launch
extern "C" void kernel_launch(void* const* d_in, const int* in_sizes, int n_in,
                              void* d_out, int out_size, void* d_ws, size_t ws_size,
                              hipStream_t stream) {
    (void)in_sizes; (void)n_in; (void)out_size; (void)ws_size;
    const float* x    = (const float*)d_in[0];
    const float* ln1g = (const float*)d_in[1];
    const float* ln1b = (const float*)d_in[2];
    const float* ln2g = (const float*)d_in[3];
    const float* ln2b = (const float*)d_in[4];
    const float* qw   = (const float*)d_in[5];
    const float* kw   = (const float*)d_in[6];
    const float* vw   = (const float*)d_in[7];
    const float* gw   = (const float*)d_in[8];
    const float* ow   = (const float*)d_in[9];
    const float* in_w = (const float*)d_in[10];
    const float* in_b = (const float*)d_in[11];
    const float* outw = (const float*)d_in[12];
    const float* outb = (const float*)d_in[13];
    float* out = (float*)d_out;
    float* ws = (float*)d_ws;

    // workspace layout (float units)
    constexpr size_t O_SIN = 0;                         // 32000
    constexpr size_t O_COS = 32000;                     // 32000
    constexpr size_t O_W   = 64000;                     // 589824 bf16 = 294912 fl
    constexpr size_t O_R1  = 358912;                    // qr -> x2
    constexpr size_t O_R2  = O_R1 + 4096000;            // kr -> qhat
    constexpr size_t O_R3  = O_R2 + 4096000;            // v  -> khat
    constexpr size_t O_R4  = O_R3 + 4096000;            // g  -> vhat
    constexpr size_t O_H   = O_R4 + 4096000;            // bf16 hi pair (2,048,000 fl) / kvp window
    constexpr size_t O_L   = O_H + 2048000;             // bf16 lo pair
    constexpr size_t O_REC = O_L + 2048000;             // 262144
    constexpr size_t O_SIG = O_REC + 262144;            // 256
    // total 21,101,312 fl = 84.4 MB

    float* sinT = ws + O_SIN;
    float* cosT = ws + O_COS;
    unsigned short* Wc = (unsigned short*)(ws + O_W);
    float* R1 = ws + O_R1;
    float* R2 = ws + O_R2;
    float* R3 = ws + O_R3;
    float* R4 = ws + O_R4;
    unsigned short* H = (unsigned short*)(ws + O_H);
    unsigned short* L = (unsigned short*)(ws + O_L);
    float* kvpf = ws + O_H;   // kvp overlaps H (dead window between proj and ret_core)
    float* recb = ws + O_REC;
    float* sigb = ws + O_SIG;

    // 0) tables + weight cast
    tab_kernel<<<125, 256, 0, stream>>>(sinT, cosT);
    wcast_kernel<<<576, 256, 0, stream>>>(qw, kw, vw, gw, ow, in_w, outw, Wc);
    // 1) LN1: x -> H/L (bf16 xn)
    ln_kernel<<<MROWS / 4, 256, 0, stream>>>(x, ln1g, ln1b, H, L, MROWS);
    // 2) proj: -> qr(R1) kr(R2) v(R3) g(R4)
    gemm_mfma<0><<<dim3(8, 125), 256, 0, stream>>>(H, L, Wc, sinT, cosT, nullptr,
                                                   nullptr, R1, R2, R3, R4);
    // 3) kv partials -> kvpf (H window; xn dead)
    kvp_kernel<<<512, 256, 0, stream>>>(R2, R3, kvpf);
    // 4) scan -> rec, sig
    scan_kernel<<<64, 256, 0, stream>>>(kvpf, recb, sigb);
    // 5) retention core -> H/L (ab hi/lo; kvp dead after scan)
    ret_core2<<<2048, 256, 0, stream>>>(R1, R2, R3, R4, recb, sigb, H, L);
    // 6) out-proj + residual: x + ab @ ow.T -> x2 (R1)
    gemm_mfma<1><<<dim3(2, 125), 256, 0, stream>>>(H, L, Wc, nullptr, nullptr,
                                                   nullptr, x, R1, nullptr, nullptr, nullptr);
    // 7) LN2: x2 -> H/L (bf16 yn)
    ln_kernel<<<MROWS / 4, 256, 0, stream>>>(R1, ln2g, ln2b, H, L, MROWS);
    // 8) qkv: -> qhat(R2) khat(R3) vhat(R4)
    gemm_mfma<2><<<dim3(6, 125), 256, 0, stream>>>(H, L, Wc, nullptr, nullptr,
                                                   in_b, nullptr, R2, R3, R4, nullptr);
    // 9) tiny attention -> H/L (att hi/lo)
    mha_attn<<<500, 256, 0, stream>>>(R2, R3, R4, H, L);
    // 10) final: x2 + att @ out_w.T + out_b -> d_out
    gemm_mfma<3><<<dim3(2, 125), 256, 0, stream>>>(H, L, Wc, nullptr, nullptr,
                                                   outb, R1, out, nullptr, nullptr, nullptr);
}

// Round 8
// 281.943 us; speedup vs baseline: 2.9527x; 1.3394x over previous
//
#include <hip/hip_runtime.h>
#include <math.h>

#define TLEN 2000
#define NSEQ 8       // B*C
#define NHEADS 8
#define KD 32
#define CHUNKN 500
#define NCHUNK 4
#define MROWS 16000  // NSEQ*TLEN
#define SCALING 0.1767766952966369f

typedef float f32x4 __attribute__((ext_vector_type(4)));
typedef short s16x8 __attribute__((ext_vector_type(8)));
typedef unsigned short u16x8 __attribute__((ext_vector_type(8)));
typedef unsigned short u16x4 __attribute__((ext_vector_type(4)));

__device__ __forceinline__ unsigned short f2bf(float f) {
    unsigned int u = __float_as_uint(f);
    unsigned int r = (u + 0x7FFFu + ((u >> 16) & 1u)) >> 16;
    return (unsigned short)r;
}
__device__ __forceinline__ float bf2f(unsigned short h) {
    return __uint_as_float(((unsigned int)h) << 16);
}
__device__ __forceinline__ unsigned int cvtpk(float lo, float hi) {
    unsigned int r;
    asm("v_cvt_pk_bf16_f32 %0, %1, %2" : "=v"(r) : "v"(lo), "v"(hi));
    return r;
}

// ---------------------------------------------------------------- tables (16 angles)
__global__ __launch_bounds__(256) void tab_kernel(float* __restrict__ sinT,
                                                  float* __restrict__ cosT) {
    int idx = blockIdx.x * 256 + threadIdx.x;
    if (idx >= TLEN * 16) return;
    int t = idx >> 4, a = idx & 15;
    float ang = powf(10000.0f, -(float)a / 15.0f);
    float th = (float)t * ang;
    sinT[idx] = sinf(th);
    cosT[idx] = cosf(th);
}

// ---------------------------------------------------------------- weight cast fp32 -> bf16 concat
__global__ __launch_bounds__(256) void wcast_kernel(
    const float* __restrict__ qw, const float* __restrict__ kw,
    const float* __restrict__ vw, const float* __restrict__ gw,
    const float* __restrict__ ow, const float* __restrict__ inw,
    const float* __restrict__ outw, unsigned short* __restrict__ W) {
    int i = blockIdx.x * 1024 + threadIdx.x * 4;
    const float* src; int off;
    if (i < 65536)       { src = qw;   off = i; }
    else if (i < 131072) { src = kw;   off = i - 65536; }
    else if (i < 196608) { src = vw;   off = i - 131072; }
    else if (i < 262144) { src = gw;   off = i - 196608; }
    else if (i < 327680) { src = ow;   off = i - 262144; }
    else if (i < 524288) { src = inw;  off = i - 327680; }
    else                 { src = outw; off = i - 524288; }
    float4 v = *(const float4*)(src + off);
    u16x4 o;
    o[0] = f2bf(v.x); o[1] = f2bf(v.y); o[2] = f2bf(v.z); o[3] = f2bf(v.w);
    *(u16x4*)(W + i) = o;
}

// ---------------------------------------------------------------- layernorm -> bf16 hi/lo
__global__ __launch_bounds__(256) void ln_kernel(const float* __restrict__ x,
                                                 const float* __restrict__ gam,
                                                 const float* __restrict__ bet,
                                                 unsigned short* __restrict__ H,
                                                 unsigned short* __restrict__ L,
                                                 int rows) {
    int wid = threadIdx.x >> 6, lane = threadIdx.x & 63;
    int row = blockIdx.x * 4 + wid;
    if (row >= rows) return;
    const float* xr = x + (size_t)row * 256;
    float4 v = *(const float4*)(xr + lane * 4);
    float s = v.x + v.y + v.z + v.w;
    #pragma unroll
    for (int o = 32; o; o >>= 1) s += __shfl_xor(s, o);
    float mu = s * (1.0f / 256.0f);
    float dx = v.x - mu, dy = v.y - mu, dz = v.z - mu, dw = v.w - mu;
    float ss = dx * dx + dy * dy + dz * dz + dw * dw;
    #pragma unroll
    for (int o = 32; o; o >>= 1) ss += __shfl_xor(ss, o);
    float rstd = rsqrtf(ss * (1.0f / 256.0f) + 1e-5f);
    float4 g4 = *(const float4*)(gam + lane * 4);
    float4 b4 = *(const float4*)(bet + lane * 4);
    float ov[4];
    ov[0] = dx * rstd * g4.x + b4.x;
    ov[1] = dy * rstd * g4.y + b4.y;
    ov[2] = dz * rstd * g4.z + b4.z;
    ov[3] = dw * rstd * g4.w + b4.w;
    u16x4 hv, lv;
    #pragma unroll
    for (int j = 0; j < 4; ++j) {
        hv[j] = f2bf(ov[j]);
        lv[j] = f2bf(ov[j] - bf2f(hv[j]));
    }
    *(u16x4*)(H + (size_t)row * 256 + lane * 4) = hv;
    *(u16x4*)(L + (size_t)row * 256 + lane * 4) = lv;
}

// ---------------------------------------------------------------- MFMA GEMM  y = A @ W.T, K=256
template <int MODE>
__global__ __launch_bounds__(256, 2) void gemm_mfma(
    const unsigned short* __restrict__ AH, const unsigned short* __restrict__ AL,
    const unsigned short* __restrict__ Wc, const float* __restrict__ sinT,
    const float* __restrict__ cosT, const float* __restrict__ bias,
    const float* __restrict__ resid, float* __restrict__ D0,
    float* __restrict__ D1, float* __restrict__ D2, float* __restrict__ D3) {
    __shared__ unsigned short Ah[128][72];
    __shared__ unsigned short Al[128][72];
    __shared__ unsigned short Bt[128][72];
    const int tid = threadIdx.x;
    const int m0 = blockIdx.y * 128, n0 = blockIdx.x * 128;
    size_t wbase;
    if constexpr (MODE == 0)      wbase = (size_t)(n0 >> 8) * 65536 + (size_t)(n0 & 255) * 256;
    else if constexpr (MODE == 1) wbase = 262144 + (size_t)n0 * 256;
    else if constexpr (MODE == 2) wbase = 327680 + (size_t)n0 * 256;
    else                          wbase = 524288 + (size_t)n0 * 256;

    const int wid = tid >> 6, lane = tid & 63;
    const int wm = wid >> 1, wn = wid & 1;
    const int lr = lane & 15, lk = lane >> 4;
    const int str = tid >> 3;         // staging row base (0..31)
    const int stc = (tid & 7) * 8;    // staging col

    f32x4 acc[4][4] = {};

    for (int kt = 0; kt < 256; kt += 64) {
        if (kt) __syncthreads();
        #pragma unroll
        for (int it = 0; it < 4; ++it) {
            int r = it * 32 + str;
            u16x8 va = *(const u16x8*)(AH + (size_t)(m0 + r) * 256 + kt + stc);
            u16x8 vl = *(const u16x8*)(AL + (size_t)(m0 + r) * 256 + kt + stc);
            u16x8 vw = *(const u16x8*)(Wc + wbase + (size_t)r * 256 + kt + stc);
            *(u16x8*)(&Ah[r][stc]) = va;
            *(u16x8*)(&Al[r][stc]) = vl;
            *(u16x8*)(&Bt[r][stc]) = vw;
        }
        __syncthreads();
        #pragma unroll
        for (int ks = 0; ks < 2; ++ks) {
            const int k0 = ks * 32 + lk * 8;
            s16x8 af[4], alf[4], bf[4];
            #pragma unroll
            for (int f = 0; f < 4; ++f) {
                af[f]  = *(const s16x8*)(&Ah[wm * 64 + f * 16 + lr][k0]);
                alf[f] = *(const s16x8*)(&Al[wm * 64 + f * 16 + lr][k0]);
                bf[f]  = *(const s16x8*)(&Bt[wn * 64 + f * 16 + lr][k0]);
            }
            #pragma unroll
            for (int fm = 0; fm < 4; ++fm)
                #pragma unroll
                for (int fn = 0; fn < 4; ++fn) {
                    acc[fm][fn] = __builtin_amdgcn_mfma_f32_16x16x32_bf16(af[fm], bf[fn], acc[fm][fn], 0, 0, 0);
                    acc[fm][fn] = __builtin_amdgcn_mfma_f32_16x16x32_bf16(alf[fm], bf[fn], acc[fm][fn], 0, 0, 0);
                }
        }
    }

    if constexpr (MODE == 0) {
        const int w = n0 >> 8;
        const float sc = (w == 1) ? SCALING : 1.0f;
        #pragma unroll
        for (int fn = 0; fn < 4; ++fn) {
            const int c = n0 + wn * 64 + fn * 16 + lr;
            const int cb = c & 255, h = cb >> 5, d0 = cb & 31;
            #pragma unroll
            for (int fm = 0; fm < 4; ++fm)
                #pragma unroll
                for (int r = 0; r < 4; ++r) {
                    const int i = m0 + wm * 64 + fm * 16 + lk * 4 + r;
                    const int b = i / TLEN, t = i - b * TLEN;
                    float v = acc[fm][fn][r] * sc;
                    if (w <= 1) {
                        float oth = __shfl_xor(v, 1);
                        float cs = cosT[t * 16 + (d0 >> 1)];
                        float sn = sinT[t * 16 + (d0 >> 1)];
                        float outv = (d0 & 1) ? fmaf(v, cs, oth * sn) : fmaf(v, cs, -(oth * sn));
                        ((w == 0) ? D0 : D1)[((size_t)(b * NHEADS + h) * TLEN + t) * KD + d0] = outv;
                    } else if (w == 2) {
                        D2[((size_t)(b * NHEADS + h) * TLEN + t) * KD + d0] = v;
                    } else {
                        D3[(size_t)i * 256 + cb] = v;
                    }
                }
        }
    } else if constexpr (MODE == 1) {
        #pragma unroll
        for (int fn = 0; fn < 4; ++fn) {
            const int c = n0 + wn * 64 + fn * 16 + lr;
            #pragma unroll
            for (int fm = 0; fm < 4; ++fm)
                #pragma unroll
                for (int r = 0; r < 4; ++r) {
                    const int i = m0 + wm * 64 + fm * 16 + lk * 4 + r;
                    D0[(size_t)i * 256 + c] = resid[(size_t)i * 256 + c] + acc[fm][fn][r];
                }
        }
    } else if constexpr (MODE == 2) {
        const int w = n0 >> 8;
        const float qs = (w == 0) ? SCALING : 1.0f;
        float* Dsel = (w == 0) ? D0 : (w == 1) ? D1 : D2;
        #pragma unroll
        for (int fn = 0; fn < 4; ++fn) {
            const int c = n0 + wn * 64 + fn * 16 + lr;
            const int cb = c & 255;
            const float bv = bias[c];
            #pragma unroll
            for (int fm = 0; fm < 4; ++fm)
                #pragma unroll
                for (int r = 0; r < 4; ++r) {
                    const int i = m0 + wm * 64 + fm * 16 + lk * 4 + r;
                    Dsel[(size_t)i * 256 + cb] = (acc[fm][fn][r] + bv) * qs;
                }
        }
    } else {
        #pragma unroll
        for (int fn = 0; fn < 4; ++fn) {
            const int c = n0 + wn * 64 + fn * 16 + lr;
            const float bv = bias[c];
            #pragma unroll
            for (int fm = 0; fm < 4; ++fm)
                #pragma unroll
                for (int r = 0; r < 4; ++r) {
                    const int i = m0 + wm * 64 + fm * 16 + lk * 4 + r;
                    D0[(size_t)i * 256 + c] = resid[(size_t)i * 256 + c] + acc[fm][fn][r] + bv;
                }
        }
    }
}

// ---------------------------------------------------------------- kv partials (2 j-subchunks)
__global__ __launch_bounds__(256) void kvp_kernel(const float* __restrict__ kr,
                                                  const float* __restrict__ v,
                                                  float* __restrict__ kvp) {
    int blk = blockIdx.x;
    int sub = blk & 1, rest = blk >> 1;
    int b = rest >> 5, n = (rest >> 3) & 3, h = rest & 7;
    int tid = threadIdx.x;
    int k = tid >> 3, d0 = (tid & 7) * 4;
    float dec = logf(1.0f - exp2f(-5.0f - (float)h));
    float lrs = (1.0f - expf(dec * (float)CHUNKN)) / (1.0f - expf(dec));
    float invl = 1.0f / lrs;
    const float* krb = kr + ((size_t)(b * NHEADS + h) * TLEN + n * CHUNKN) * KD;
    const float* vb = v + ((size_t)(b * NHEADS + h) * TLEN + n * CHUNKN) * KD;
    float a0 = 0, a1 = 0, a2 = 0, a3 = 0;
    int j0 = sub * 250;
    for (int j = j0; j < j0 + 250; ++j) {
        float kj = krb[(size_t)j * KD + k];
        float vd = expf(dec * (float)(CHUNKN - 1 - j)) * invl;
        float w = kj * vd;
        float4 vv = *(const float4*)(vb + (size_t)j * KD + d0);
        a0 = fmaf(w, vv.x, a0); a1 = fmaf(w, vv.y, a1);
        a2 = fmaf(w, vv.z, a2); a3 = fmaf(w, vv.w, a3);
    }
    float* dst = kvp + ((size_t)rest * 2 + sub) * 1024 + k * 32 + d0;
    dst[0] = a0; dst[1] = a1; dst[2] = a2; dst[3] = a3;
}

// ---------------------------------------------------------------- cross-chunk scan
__global__ __launch_bounds__(256) void scan_kernel(const float* __restrict__ kvp,
                                                   float* __restrict__ rec,
                                                   float* __restrict__ sig) {
    __shared__ float cs[32];
    __shared__ float ssig;
    int blk = blockIdx.x;
    int b = blk >> 3, h = blk & 7;
    int tid = threadIdx.x;
    float dec = logf(1.0f - exp2f(-5.0f - (float)h));
    float cd = expf(dec * (float)CHUNKN);
    float S0 = 0, S1 = 0, S2 = 0, S3 = 0;
    float sigma = 1.0f;
    for (int n = 0; n < NCHUNK; ++n) {
        int rest = b * 32 + n * 8 + h;
        size_t rbase = (size_t)rest * 1024;
        size_t pbase = (size_t)rest * 2048;
        rec[rbase + tid] = S0;
        rec[rbase + tid + 256] = S1;
        rec[rbase + tid + 512] = S2;
        rec[rbase + tid + 768] = S3;
        if (tid == 0) sig[rest] = sigma;
        float k0 = 0, k1 = 0, k2 = 0, k3 = 0;
        #pragma unroll
        for (int s = 0; s < 2; ++s) {
            k0 += kvp[pbase + s * 1024 + tid];
            k1 += kvp[pbase + s * 1024 + tid + 256];
            k2 += kvp[pbase + s * 1024 + tid + 512];
            k3 += kvp[pbase + s * 1024 + tid + 768];
        }
        S0 = S0 * cd + k0;
        S1 = S1 * cd + k1;
        S2 = S2 * cd + k2;
        S3 = S3 * cd + k3;
        if (tid < 32) cs[tid] = 0.f;
        __syncthreads();
        float part = fabsf(S0) + fabsf(S1) + fabsf(S2) + fabsf(S3);
        atomicAdd(&cs[tid & 31], part);
        __syncthreads();
        if (tid == 0) {
            float m = cs[0];
            for (int d = 1; d < 32; ++d) m = fmaxf(m, cs[d]);
            ssig = fmaxf(m, 1.0f);
        }
        __syncthreads();
        sigma = ssig;
    }
}

// ---------------------------------------------------------------- retention core v3 (MFMA)
// grid = 1024: blockIdx = band_rev*256 + chunk; band u = 3 - (blockIdx>>8) (heavy first)
// block = 256 (4 waves); wave owns 32 q-rows: i = u*128 + wid*32 + fi*16 + (lane&15)
// Swapped QK^T: S^T = mfma(A=K_scaled, B=Q)  ->  lane col = q-row (causal mask lane-local)
__global__ __launch_bounds__(256, 2) void ret_core3(
    const float* __restrict__ qr, const float* __restrict__ kr,
    const float* __restrict__ v, const float* __restrict__ g,
    const float* __restrict__ rec, const float* __restrict__ sig,
    unsigned short* __restrict__ ABH, unsigned short* __restrict__ ABL) {
    __shared__ unsigned short Kt[64][40];    // K*e^{-dec j}  [j][d]
    __shared__ unsigned short Vt[32][72];    // V^T           [d][j]
    __shared__ unsigned short SpH[32][40];   // S_prev^T hi   [d][k]
    __shared__ unsigned short SpL[32][40];   // S_prev^T lo
    __shared__ unsigned short Pl[128][72];   // P (loop) / out hi+lo (epilogue)

    const int u = 3 - (int)(blockIdx.x >> 8);
    const int chunk = blockIdx.x & 255;
    const int b = chunk >> 5, n = (chunk >> 3) & 3, h = chunk & 7;
    const int tid = threadIdx.x;
    const int wid = tid >> 6, lane = tid & 63;
    const int c = lane & 15, gq = lane >> 4;
    const float dec = logf(1.0f - exp2f(-5.0f - (float)h));
    const float ndec = -dec;
    const size_t cbase = ((size_t)(b * NHEADS + h) * TLEN + n * CHUNKN) * KD;
    const int i0 = u * 128 + wid * 32;
    const int NT = 2 * u + 2;
    const int jtmax_w = (i0 + 31) >> 6;

    // ---- Q fragments (B-operand): col=lane&15=i, k=gq*8+e=d; exact via hi/lo
    s16x8 qh[2], ql[2];
    #pragma unroll
    for (int fi = 0; fi < 2; ++fi) {
        const float* qp = qr + cbase + (size_t)(i0 + fi * 16 + c) * KD + gq * 8;
        float4 a = *(const float4*)qp;
        float4 bq = *(const float4*)(qp + 4);
        float vals[8] = {a.x, a.y, a.z, a.w, bq.x, bq.y, bq.z, bq.w};
        u16x8 hv, lv;
        #pragma unroll
        for (int j = 0; j < 8; ++j) {
            hv[j] = f2bf(vals[j]);
            lv[j] = f2bf(vals[j] - bf2f(hv[j]));
        }
        qh[fi] = *(s16x8*)&hv;
        ql[fi] = *(s16x8*)&lv;
    }

    // ---- stage S_prev^T hi/lo (rec is [k][d] row-major, 32x32)
    {
        int e0 = tid * 4;
        int k = e0 >> 5, d0 = e0 & 31;
        float4 sv = *(const float4*)(rec + (size_t)chunk * 1024 + e0);
        float se[4] = {sv.x, sv.y, sv.z, sv.w};
        #pragma unroll
        for (int j = 0; j < 4; ++j) {
            unsigned short hb = f2bf(se[j]);
            SpH[d0 + j][k] = hb;
            SpL[d0 + j][k] = f2bf(se[j] - bf2f(hb));
        }
    }

    f32x4 ot[2][2] = {};   // PV^T accum: d = fd*16+gq*4+reg, i = fi*16+c
    float absI[2] = {0.f, 0.f};

    for (int jt = 0; jt < NT; ++jt) {
        if (jt) __syncthreads();
        {   // stage K (scaled) and V^T: thread -> row jl, 8 d's
            int jl = tid >> 2, d0 = (tid & 3) * 8;
            int jg = jt * 64 + jl;
            float ej = expf(ndec * (float)jg);
            const float* kp = kr + cbase + (size_t)jg * KD + d0;
            const float* vp = v + cbase + (size_t)jg * KD + d0;
            float4 k0 = *(const float4*)kp, k1 = *(const float4*)(kp + 4);
            float4 v0 = *(const float4*)vp, v1 = *(const float4*)(vp + 4);
            u16x8 kb;
            kb[0] = f2bf(k0.x * ej); kb[1] = f2bf(k0.y * ej);
            kb[2] = f2bf(k0.z * ej); kb[3] = f2bf(k0.w * ej);
            kb[4] = f2bf(k1.x * ej); kb[5] = f2bf(k1.y * ej);
            kb[6] = f2bf(k1.z * ej); kb[7] = f2bf(k1.w * ej);
            *(u16x8*)&Kt[jl][d0] = kb;
            Vt[d0 + 0][jl] = f2bf(v0.x); Vt[d0 + 1][jl] = f2bf(v0.y);
            Vt[d0 + 2][jl] = f2bf(v0.z); Vt[d0 + 3][jl] = f2bf(v0.w);
            Vt[d0 + 4][jl] = f2bf(v1.x); Vt[d0 + 5][jl] = f2bf(v1.y);
            Vt[d0 + 6][jl] = f2bf(v1.z); Vt[d0 + 7][jl] = f2bf(v1.w);
        }
        __syncthreads();
        if (jt <= jtmax_w) {
            // QK^T -> S^T frags [jf][fi]
            f32x4 st[4][2] = {};
            s16x8 ka[4];
            #pragma unroll
            for (int jf = 0; jf < 4; ++jf)
                ka[jf] = *(const s16x8*)&Kt[jf * 16 + c][gq * 8];
            #pragma unroll
            for (int jf = 0; jf < 4; ++jf)
                #pragma unroll
                for (int fi = 0; fi < 2; ++fi) {
                    st[jf][fi] = __builtin_amdgcn_mfma_f32_16x16x32_bf16(ka[jf], qh[fi], st[jf][fi], 0, 0, 0);
                    st[jf][fi] = __builtin_amdgcn_mfma_f32_16x16x32_bf16(ka[jf], ql[fi], st[jf][fi], 0, 0, 0);
                }
            // mask (diagonal tiles) + abs row-sum + pack P -> LDS
            const bool domask = (jt * 64 + 63 > i0);
            #pragma unroll
            for (int jf = 0; jf < 4; ++jf)
                #pragma unroll
                for (int fi = 0; fi < 2; ++fi) {
                    const int ii = i0 + fi * 16 + c;
                    if (domask) {
                        #pragma unroll
                        for (int r = 0; r < 4; ++r) {
                            int jg = jt * 64 + jf * 16 + gq * 4 + r;
                            if (jg > ii) st[jf][fi][r] = 0.f;
                        }
                    }
                    absI[fi] += (fabsf(st[jf][fi][0]) + fabsf(st[jf][fi][1])) +
                                (fabsf(st[jf][fi][2]) + fabsf(st[jf][fi][3]));
                    uint2 pw;
                    pw.x = cvtpk(st[jf][fi][0], st[jf][fi][1]);
                    pw.y = cvtpk(st[jf][fi][2], st[jf][fi][3]);
                    *(uint2*)&Pl[wid * 32 + fi * 16 + c][jf * 16 + gq * 4] = pw;
                }
            // PV^T += V^T · P^T
            #pragma unroll
            for (int js = 0; js < 2; ++js) {
                s16x8 va0 = *(const s16x8*)&Vt[c][js * 32 + gq * 8];
                s16x8 va1 = *(const s16x8*)&Vt[16 + c][js * 32 + gq * 8];
                #pragma unroll
                for (int fi = 0; fi < 2; ++fi) {
                    s16x8 pb = *(const s16x8*)&Pl[wid * 32 + fi * 16 + c][js * 32 + gq * 8];
                    ot[0][fi] = __builtin_amdgcn_mfma_f32_16x16x32_bf16(va0, pb, ot[0][fi], 0, 0, 0);
                    ot[1][fi] = __builtin_amdgcn_mfma_f32_16x16x32_bf16(va1, pb, ot[1][fi], 0, 0, 0);
                }
            }
        }
    }

    // ---- cross term X^T = S_prev^T · Q  (hi/lo on Sp, hi/lo on q, drop lo·lo)
    f32x4 xt[2][2] = {};
    #pragma unroll
    for (int fd = 0; fd < 2; ++fd) {
        s16x8 sh = *(const s16x8*)&SpH[fd * 16 + c][gq * 8];
        s16x8 sl = *(const s16x8*)&SpL[fd * 16 + c][gq * 8];
        #pragma unroll
        for (int fi = 0; fi < 2; ++fi) {
            xt[fd][fi] = __builtin_amdgcn_mfma_f32_16x16x32_bf16(sh, qh[fi], xt[fd][fi], 0, 0, 0);
            xt[fd][fi] = __builtin_amdgcn_mfma_f32_16x16x32_bf16(sh, ql[fi], xt[fd][fi], 0, 0, 0);
            xt[fd][fi] = __builtin_amdgcn_mfma_f32_16x16x32_bf16(sl, qh[fi], xt[fd][fi], 0, 0, 0);
        }
    }

    // ---- per-row scales + combine + group-norm + silu -> Pl (hi cols 0..31, lo cols 36..67)
    const float er = expf(dec);
    const float inv1mr = 1.0f / (1.0f - er);
    const float lrs = (1.0f - expf(dec * (float)CHUNKN)) * inv1mr;
    const float sgp = sig[chunk];
    #pragma unroll
    for (int fi = 0; fi < 2; ++fi) {
        absI[fi] += __shfl_xor(absI[fi], 16);
        absI[fi] += __shfl_xor(absI[fi], 32);
        const int ii = i0 + fi * 16 + c;
        float rowsum = (1.0f - expf(dec * (float)(ii + 1))) * inv1mr;
        float iscale = rsqrtf(rowsum);
        float f_i = expf(dec * (float)ii) * iscale;
        float inner = fmaxf(absI[fi] * f_i, 1.0f);
        float alls = fmaxf(inner, sgp);
        float qd = expf(dec * (float)(ii + 1)) * lrs * iscale;
        float inva = 1.0f / alls;
        float vals[2][4];
        float ms = 0.f;
        #pragma unroll
        for (int fd = 0; fd < 2; ++fd)
            #pragma unroll
            for (int r = 0; r < 4; ++r) {
                float t = (ot[fd][fi][r] * f_i + xt[fd][fi][r] * qd) * inva;
                vals[fd][r] = t;
                ms += t * t;
            }
        ms += __shfl_xor(ms, 16);
        ms += __shfl_xor(ms, 32);
        float rn = rsqrtf(ms * (1.0f / 32.0f) + 1e-6f);
        const int tg = n * CHUNKN + ii;
        const float* gp = g + ((size_t)b * TLEN + tg) * 256 + h * KD;
        #pragma unroll
        for (int fd = 0; fd < 2; ++fd) {
            float4 gv = *(const float4*)(gp + fd * 16 + gq * 4);
            float ge[4] = {gv.x, gv.y, gv.z, gv.w};
            unsigned short hb[4], lb[4];
            #pragma unroll
            for (int r = 0; r < 4; ++r) {
                float sg = ge[r] / (1.0f + expf(-ge[r]));
                float ov = sg * vals[fd][r] * rn;
                hb[r] = f2bf(ov);
                lb[r] = f2bf(ov - bf2f(hb[r]));
            }
            uint2 ph, plw;
            ph.x = (unsigned int)hb[0] | ((unsigned int)hb[1] << 16);
            ph.y = (unsigned int)hb[2] | ((unsigned int)hb[3] << 16);
            plw.x = (unsigned int)lb[0] | ((unsigned int)lb[1] << 16);
            plw.y = (unsigned int)lb[2] | ((unsigned int)lb[3] << 16);
            *(uint2*)&Pl[wid * 32 + fi * 16 + c][fd * 16 + gq * 4] = ph;
            *(uint2*)&Pl[wid * 32 + fi * 16 + c][36 + fd * 16 + gq * 4] = plw;
        }
    }
    __syncthreads();
    // ---- coalesced copy out
    {
        int r = tid & 127, half = tid >> 7;
        int ig = u * 128 + r;
        if (ig < CHUNKN) {
            unsigned short* D = half ? ABL : ABH;
            size_t dst = ((size_t)b * TLEN + n * CHUNKN + ig) * 256 + h * KD;
            #pragma unroll
            for (int k = 0; k < 4; ++k) {
                u16x4 a = *(const u16x4*)&Pl[r][half * 36 + k * 8];
                u16x4 bq = *(const u16x4*)&Pl[r][half * 36 + k * 8 + 4];
                u16x8 w;
                w[0] = a[0]; w[1] = a[1]; w[2] = a[2]; w[3] = a[3];
                w[4] = bq[0]; w[5] = bq[1]; w[6] = bq[2]; w[7] = bq[3];
                *(u16x8*)(D + dst + k * 8) = w;
            }
        }
    }
}

// ---------------------------------------------------------------- tiny MHA (seq len 4) -> bf16 hi/lo
__global__ __launch_bounds__(256) void mha_attn(const float* __restrict__ qh,
                                                const float* __restrict__ kh,
                                                const float* __restrict__ vh,
                                                unsigned short* __restrict__ OH,
                                                unsigned short* __restrict__ OL) {
    int gidx = blockIdx.x * 256 + threadIdx.x;
    if (gidx >= 2 * TLEN * NHEADS * 4) return;
    int i = gidx & 3;
    int h = (gidx >> 2) & 7;
    int rest = gidx >> 5;  // b*2000 + t
    int t = rest % TLEN;
    int b = rest / TLEN;
    size_t rows[4];
    #pragma unroll
    for (int c = 0; c < 4; ++c) rows[c] = ((size_t)(b * 4 + c) * TLEN + t);
    const float4* q4 = (const float4*)(qh + rows[i] * 256 + h * 32);
    float4 q[8];
    #pragma unroll
    for (int r = 0; r < 8; ++r) q[r] = q4[r];
    float s[4];
    #pragma unroll
    for (int j = 0; j < 4; ++j) {
        const float4* k4 = (const float4*)(kh + rows[j] * 256 + h * 32);
        float a0 = 0, a1 = 0, a2 = 0, a3 = 0;
        #pragma unroll
        for (int r = 0; r < 8; ++r) {
            float4 kk = k4[r];
            a0 = fmaf(q[r].x, kk.x, a0);
            a1 = fmaf(q[r].y, kk.y, a1);
            a2 = fmaf(q[r].z, kk.z, a2);
            a3 = fmaf(q[r].w, kk.w, a3);
        }
        s[j] = (a0 + a1) + (a2 + a3);
    }
    float m = fmaxf(fmaxf(s[0], s[1]), fmaxf(s[2], s[3]));
    float p[4], den = 0.f;
    #pragma unroll
    for (int j = 0; j < 4; ++j) { p[j] = expf(s[j] - m); den += p[j]; }
    float inv = 1.0f / den;
    float4 o[8];
    #pragma unroll
    for (int r = 0; r < 8; ++r) o[r] = make_float4(0.f, 0.f, 0.f, 0.f);
    #pragma unroll
    for (int j = 0; j < 4; ++j) {
        float wj = p[j] * inv;
        const float4* v4 = (const float4*)(vh + rows[j] * 256 + h * 32);
        #pragma unroll
        for (int r = 0; r < 8; ++r) {
            float4 vv = v4[r];
            o[r].x = fmaf(wj, vv.x, o[r].x);
            o[r].y = fmaf(wj, vv.y, o[r].y);
            o[r].z = fmaf(wj, vv.z, o[r].z);
            o[r].w = fmaf(wj, vv.w, o[r].w);
        }
    }
    #pragma unroll
    for (int r = 0; r < 8; ++r) {
        float vv[4] = {o[r].x, o[r].y, o[r].z, o[r].w};
        u16x4 hv, lv;
        #pragma unroll
        for (int j = 0; j < 4; ++j) {
            hv[j] = f2bf(vv[j]);
            lv[j] = f2bf(vv[j] - bf2f(hv[j]));
        }
        *(u16x4*)(OH + rows[i] * 256 + h * 32 + r * 4) = hv;
        *(u16x4*)(OL + rows[i] * 256 + h * 32 + r * 4) = lv;
    }
}

// ---------------------------------------------------------------- launch
extern "C" void kernel_launch(void* const* d_in, const int* in_sizes, int n_in,
                              void* d_out, int out_size, void* d_ws, size_t ws_size,
                              hipStream_t stream) {
    (void)in_sizes; (void)n_in; (void)out_size; (void)ws_size;
    const float* x    = (const float*)d_in[0];
    const float* ln1g = (const float*)d_in[1];
    const float* ln1b = (const float*)d_in[2];
    const float* ln2g = (const float*)d_in[3];
    const float* ln2b = (const float*)d_in[4];
    const float* qw   = (const float*)d_in[5];
    const float* kw   = (const float*)d_in[6];
    const float* vw   = (const float*)d_in[7];
    const float* gw   = (const float*)d_in[8];
    const float* ow   = (const float*)d_in[9];
    const float* in_w = (const float*)d_in[10];
    const float* in_b = (const float*)d_in[11];
    const float* outw = (const float*)d_in[12];
    const float* outb = (const float*)d_in[13];
    float* out = (float*)d_out;
    float* ws = (float*)d_ws;

    // workspace layout (float units)
    constexpr size_t O_SIN = 0;                         // 32000
    constexpr size_t O_COS = 32000;                     // 32000
    constexpr size_t O_W   = 64000;                     // 589824 bf16 = 294912 fl
    constexpr size_t O_R1  = 358912;                    // qr -> x2
    constexpr size_t O_R2  = O_R1 + 4096000;            // kr -> qhat
    constexpr size_t O_R3  = O_R2 + 4096000;            // v  -> khat
    constexpr size_t O_R4  = O_R3 + 4096000;            // g  -> vhat
    constexpr size_t O_H   = O_R4 + 4096000;            // bf16 hi pair / kvp window
    constexpr size_t O_L   = O_H + 2048000;             // bf16 lo pair
    constexpr size_t O_REC = O_L + 2048000;             // 262144
    constexpr size_t O_SIG = O_REC + 262144;            // 256

    float* sinT = ws + O_SIN;
    float* cosT = ws + O_COS;
    unsigned short* Wc = (unsigned short*)(ws + O_W);
    float* R1 = ws + O_R1;
    float* R2 = ws + O_R2;
    float* R3 = ws + O_R3;
    float* R4 = ws + O_R4;
    unsigned short* H = (unsigned short*)(ws + O_H);
    unsigned short* L = (unsigned short*)(ws + O_L);
    float* kvpf = ws + O_H;
    float* recb = ws + O_REC;
    float* sigb = ws + O_SIG;

    tab_kernel<<<125, 256, 0, stream>>>(sinT, cosT);
    wcast_kernel<<<576, 256, 0, stream>>>(qw, kw, vw, gw, ow, in_w, outw, Wc);
    ln_kernel<<<MROWS / 4, 256, 0, stream>>>(x, ln1g, ln1b, H, L, MROWS);
    gemm_mfma<0><<<dim3(8, 125), 256, 0, stream>>>(H, L, Wc, sinT, cosT, nullptr,
                                                   nullptr, R1, R2, R3, R4);
    kvp_kernel<<<512, 256, 0, stream>>>(R2, R3, kvpf);
    scan_kernel<<<64, 256, 0, stream>>>(kvpf, recb, sigb);
    ret_core3<<<1024, 256, 0, stream>>>(R1, R2, R3, R4, recb, sigb, H, L);
    gemm_mfma<1><<<dim3(2, 125), 256, 0, stream>>>(H, L, Wc, nullptr, nullptr,
                                                   nullptr, x, R1, nullptr, nullptr, nullptr);
    ln_kernel<<<MROWS / 4, 256, 0, stream>>>(R1, ln2g, ln2b, H, L, MROWS);
    gemm_mfma<2><<<dim3(6, 125), 256, 0, stream>>>(H, L, Wc, nullptr, nullptr,
                                                   in_b, nullptr, R2, R3, R4, nullptr);
    mha_attn<<<500, 256, 0, stream>>>(R2, R3, R4, H, L);
    gemm_mfma<3><<<dim3(2, 125), 256, 0, stream>>>(H, L, Wc, nullptr, nullptr,
                                                   outb, R1, out, nullptr, nullptr, nullptr);
}

// Round 10
// 271.058 us; speedup vs baseline: 3.0713x; 1.0402x over previous
//
#include <hip/hip_runtime.h>
#include <math.h>

#define TLEN 2000
#define NSEQ 8       // B*C
#define NHEADS 8
#define KD 32
#define CHUNKN 500
#define NCHUNK 4
#define MROWS 16000  // NSEQ*TLEN
#define SCALING 0.1767766952966369f

typedef float f32x4 __attribute__((ext_vector_type(4)));
typedef short s16x8 __attribute__((ext_vector_type(8)));
typedef unsigned short u16x8 __attribute__((ext_vector_type(8)));
typedef unsigned short u16x4 __attribute__((ext_vector_type(4)));

__device__ __forceinline__ unsigned short f2bf(float f) {
    unsigned int u = __float_as_uint(f);
    unsigned int r = (u + 0x7FFFu + ((u >> 16) & 1u)) >> 16;
    return (unsigned short)r;
}
__device__ __forceinline__ float bf2f(unsigned short h) {
    return __uint_as_float(((unsigned int)h) << 16);
}
__device__ __forceinline__ unsigned int cvtpk(float lo, float hi) {
    unsigned int r;
    asm("v_cvt_pk_bf16_f32 %0, %1, %2" : "=v"(r) : "v"(lo), "v"(hi));
    return r;
}

// ---------------------------------------------------------------- tables (16 angles)
__global__ __launch_bounds__(256) void tab_kernel(float* __restrict__ sinT,
                                                  float* __restrict__ cosT) {
    int idx = blockIdx.x * 256 + threadIdx.x;
    if (idx >= TLEN * 16) return;
    int t = idx >> 4, a = idx & 15;
    float ang = powf(10000.0f, -(float)a / 15.0f);
    float th = (float)t * ang;
    sinT[idx] = sinf(th);
    cosT[idx] = cosf(th);
}

// ---------------------------------------------------------------- weight cast fp32 -> bf16 concat
__global__ __launch_bounds__(256) void wcast_kernel(
    const float* __restrict__ qw, const float* __restrict__ kw,
    const float* __restrict__ vw, const float* __restrict__ gw,
    const float* __restrict__ ow, const float* __restrict__ inw,
    const float* __restrict__ outw, unsigned short* __restrict__ W) {
    int i = blockIdx.x * 1024 + threadIdx.x * 4;
    const float* src; int off;
    if (i < 65536)       { src = qw;   off = i; }
    else if (i < 131072) { src = kw;   off = i - 65536; }
    else if (i < 196608) { src = vw;   off = i - 131072; }
    else if (i < 262144) { src = gw;   off = i - 196608; }
    else if (i < 327680) { src = ow;   off = i - 262144; }
    else if (i < 524288) { src = inw;  off = i - 327680; }
    else                 { src = outw; off = i - 524288; }
    float4 v = *(const float4*)(src + off);
    u16x4 o;
    o[0] = f2bf(v.x); o[1] = f2bf(v.y); o[2] = f2bf(v.z); o[3] = f2bf(v.w);
    *(u16x4*)(W + i) = o;
}

// ---------------------------------------------------------------- layernorm -> bf16 hi/lo
__global__ __launch_bounds__(256) void ln_kernel(const float* __restrict__ x,
                                                 const float* __restrict__ gam,
                                                 const float* __restrict__ bet,
                                                 unsigned short* __restrict__ H,
                                                 unsigned short* __restrict__ L,
                                                 int rows) {
    int wid = threadIdx.x >> 6, lane = threadIdx.x & 63;
    int row = blockIdx.x * 4 + wid;
    if (row >= rows) return;
    const float* xr = x + (size_t)row * 256;
    float4 v = *(const float4*)(xr + lane * 4);
    float s = v.x + v.y + v.z + v.w;
    #pragma unroll
    for (int o = 32; o; o >>= 1) s += __shfl_xor(s, o);
    float mu = s * (1.0f / 256.0f);
    float dx = v.x - mu, dy = v.y - mu, dz = v.z - mu, dw = v.w - mu;
    float ss = dx * dx + dy * dy + dz * dz + dw * dw;
    #pragma unroll
    for (int o = 32; o; o >>= 1) ss += __shfl_xor(ss, o);
    float rstd = rsqrtf(ss * (1.0f / 256.0f) + 1e-5f);
    float4 g4 = *(const float4*)(gam + lane * 4);
    float4 b4 = *(const float4*)(bet + lane * 4);
    float ov[4];
    ov[0] = dx * rstd * g4.x + b4.x;
    ov[1] = dy * rstd * g4.y + b4.y;
    ov[2] = dz * rstd * g4.z + b4.z;
    ov[3] = dw * rstd * g4.w + b4.w;
    u16x4 hv, lv;
    #pragma unroll
    for (int j = 0; j < 4; ++j) {
        hv[j] = f2bf(ov[j]);
        lv[j] = f2bf(ov[j] - bf2f(hv[j]));
    }
    *(u16x4*)(H + (size_t)row * 256 + lane * 4) = hv;
    *(u16x4*)(L + (size_t)row * 256 + lane * 4) = lv;
}

// ---------------------------------------------------------------- MFMA GEMM  y = A @ W.T, K=256
// A = bf16 hi/lo pair (exact fp32); W bf16.
// MODE 0: proj -> q hi/lo (U0,U1), k (U2), v (U3) bf16 head-layout (rotary, k*SCALING);
//         g (U4) bf16 row-layout. LDS-staged coalesced stores.
// MODE 1: F0 = resid + acc (fp32 row-layout)
// MODE 2: qkv+bias bf16 row-layout -> U0,U1,U2 (q*SCALING). LDS-staged.
// MODE 3: F0 = resid + acc + bias (fp32)
template <int MODE>
__global__ __launch_bounds__(256, 2) void gemm_mfma(
    const unsigned short* __restrict__ AH, const unsigned short* __restrict__ AL,
    const unsigned short* __restrict__ Wc, const float* __restrict__ sinT,
    const float* __restrict__ cosT, const float* __restrict__ bias,
    const float* __restrict__ resid, float* __restrict__ F0,
    unsigned short* __restrict__ U0, unsigned short* __restrict__ U1,
    unsigned short* __restrict__ U2, unsigned short* __restrict__ U3,
    unsigned short* __restrict__ U4) {
    __shared__ unsigned short Ah[128][72];
    __shared__ unsigned short Al[128][72];
    __shared__ unsigned short Bt[128][72];
    const int tid = threadIdx.x;
    const int m0 = blockIdx.y * 128, n0 = blockIdx.x * 128;
    size_t wbase;
    if constexpr (MODE == 0)      wbase = (size_t)(n0 >> 8) * 65536 + (size_t)(n0 & 255) * 256;
    else if constexpr (MODE == 1) wbase = 262144 + (size_t)n0 * 256;
    else if constexpr (MODE == 2) wbase = 327680 + (size_t)n0 * 256;
    else                          wbase = 524288 + (size_t)n0 * 256;

    const int wid = tid >> 6, lane = tid & 63;
    const int wm = wid >> 1, wn = wid & 1;
    const int lr = lane & 15, lk = lane >> 4;
    const int str = tid >> 3;
    const int stc = (tid & 7) * 8;

    f32x4 acc[4][4] = {};

    for (int kt = 0; kt < 256; kt += 64) {
        if (kt) __syncthreads();
        #pragma unroll
        for (int it = 0; it < 4; ++it) {
            int r = it * 32 + str;
            u16x8 va = *(const u16x8*)(AH + (size_t)(m0 + r) * 256 + kt + stc);
            u16x8 vl = *(const u16x8*)(AL + (size_t)(m0 + r) * 256 + kt + stc);
            u16x8 vw = *(const u16x8*)(Wc + wbase + (size_t)r * 256 + kt + stc);
            *(u16x8*)(&Ah[r][stc]) = va;
            *(u16x8*)(&Al[r][stc]) = vl;
            *(u16x8*)(&Bt[r][stc]) = vw;
        }
        __syncthreads();
        #pragma unroll
        for (int ks = 0; ks < 2; ++ks) {
            const int k0 = ks * 32 + lk * 8;
            s16x8 af[4], alf[4], bf[4];
            #pragma unroll
            for (int f = 0; f < 4; ++f) {
                af[f]  = *(const s16x8*)(&Ah[wm * 64 + f * 16 + lr][k0]);
                alf[f] = *(const s16x8*)(&Al[wm * 64 + f * 16 + lr][k0]);
                bf[f]  = *(const s16x8*)(&Bt[wn * 64 + f * 16 + lr][k0]);
            }
            #pragma unroll
            for (int fm = 0; fm < 4; ++fm)
                #pragma unroll
                for (int fn = 0; fn < 4; ++fn) {
                    acc[fm][fn] = __builtin_amdgcn_mfma_f32_16x16x32_bf16(af[fm], bf[fn], acc[fm][fn], 0, 0, 0);
                    acc[fm][fn] = __builtin_amdgcn_mfma_f32_16x16x32_bf16(alf[fm], bf[fn], acc[fm][fn], 0, 0, 0);
                }
        }
    }

    if constexpr (MODE == 0) {
        const int w = n0 >> 8;  // block-uniform: 0=q 1=k 2=v 3=g
        if (w <= 1) {           // rotary (+ k scaling), in-place on acc
            const float sc = (w == 1) ? SCALING : 1.0f;
            #pragma unroll
            for (int fn = 0; fn < 4; ++fn) {
                const int c = n0 + wn * 64 + fn * 16 + lr;
                const int d0 = c & 31;
                #pragma unroll
                for (int fm = 0; fm < 4; ++fm)
                    #pragma unroll
                    for (int r = 0; r < 4; ++r) {
                        const int i = m0 + wm * 64 + fm * 16 + lk * 4 + r;
                        const int t = i % TLEN;
                        float vraw = acc[fm][fn][r] * sc;
                        float oth = __shfl_xor(vraw, 1);
                        float cs = cosT[t * 16 + (d0 >> 1)];
                        float sn = sinT[t * 16 + (d0 >> 1)];
                        acc[fm][fn][r] = (d0 & 1) ? fmaf(vraw, cs, oth * sn)
                                                  : fmaf(vraw, cs, -(oth * sn));
                    }
            }
        }
        unsigned short* Dsel = (w == 0) ? U0 : (w == 1) ? U2 : (w == 2) ? U3 : U4;
        for (int half = 0; half < 2; ++half) {
            const int np = (w == 0) ? 2 : 1;
            for (int pass = 0; pass < np; ++pass) {
                __syncthreads();
                if (wn == half) {
                    #pragma unroll
                    for (int fn = 0; fn < 4; ++fn)
                        #pragma unroll
                        for (int fm = 0; fm < 4; ++fm)
                            #pragma unroll
                            for (int r = 0; r < 4; ++r) {
                                float x = acc[fm][fn][r];
                                unsigned short hb = f2bf(x);
                                unsigned short ob = pass ? f2bf(x - bf2f(hb)) : hb;
                                Ah[wm * 64 + fm * 16 + lk * 4 + r][fn * 16 + lr] = ob;
                            }
                }
                __syncthreads();
                unsigned short* D = (w == 0 && pass) ? U1 : Dsel;
                #pragma unroll
                for (int it = 0; it < 4; ++it) {
                    int flat = it * 2048 + tid * 8;
                    int r = flat >> 6, cl = flat & 63;
                    u16x8 val = *(const u16x8*)&Ah[r][cl];
                    int i = m0 + r;
                    int cb = (n0 & 255) + half * 64 + cl;
                    if (w <= 2) {
                        int bb = i / TLEN, t = i - bb * TLEN;
                        int hh = cb >> 5, d0 = cb & 31;
                        *(u16x8*)(D + ((size_t)(bb * NHEADS + hh) * TLEN + t) * KD + d0) = val;
                    } else {
                        *(u16x8*)(D + (size_t)i * 256 + cb) = val;
                    }
                }
            }
        }
    } else if constexpr (MODE == 1) {
        #pragma unroll
        for (int fn = 0; fn < 4; ++fn) {
            const int c = n0 + wn * 64 + fn * 16 + lr;
            #pragma unroll
            for (int fm = 0; fm < 4; ++fm)
                #pragma unroll
                for (int r = 0; r < 4; ++r) {
                    const int i = m0 + wm * 64 + fm * 16 + lk * 4 + r;
                    F0[(size_t)i * 256 + c] = resid[(size_t)i * 256 + c] + acc[fm][fn][r];
                }
        }
    } else if constexpr (MODE == 2) {
        const int w = n0 >> 8;  // 0=qhat 1=khat 2=vhat
        const float qs = (w == 0) ? SCALING : 1.0f;
        unsigned short* Dsel = (w == 0) ? U0 : (w == 1) ? U1 : U2;
        #pragma unroll
        for (int fn = 0; fn < 4; ++fn) {
            const int c = n0 + wn * 64 + fn * 16 + lr;
            const float bv = bias[c];
            #pragma unroll
            for (int fm = 0; fm < 4; ++fm)
                #pragma unroll
                for (int r = 0; r < 4; ++r)
                    acc[fm][fn][r] = (acc[fm][fn][r] + bv) * qs;
        }
        for (int half = 0; half < 2; ++half) {
            __syncthreads();
            if (wn == half) {
                #pragma unroll
                for (int fn = 0; fn < 4; ++fn)
                    #pragma unroll
                    for (int fm = 0; fm < 4; ++fm)
                        #pragma unroll
                        for (int r = 0; r < 4; ++r)
                            Ah[wm * 64 + fm * 16 + lk * 4 + r][fn * 16 + lr] =
                                f2bf(acc[fm][fn][r]);
            }
            __syncthreads();
            #pragma unroll
            for (int it = 0; it < 4; ++it) {
                int flat = it * 2048 + tid * 8;
                int r = flat >> 6, cl = flat & 63;
                u16x8 val = *(const u16x8*)&Ah[r][cl];
                int i = m0 + r;
                int cb = (n0 & 255) + half * 64 + cl;
                *(u16x8*)(Dsel + (size_t)i * 256 + cb) = val;
            }
        }
    } else {
        #pragma unroll
        for (int fn = 0; fn < 4; ++fn) {
            const int c = n0 + wn * 64 + fn * 16 + lr;
            const float bv = bias[c];
            #pragma unroll
            for (int fm = 0; fm < 4; ++fm)
                #pragma unroll
                for (int r = 0; r < 4; ++r) {
                    const int i = m0 + wm * 64 + fm * 16 + lk * 4 + r;
                    F0[(size_t)i * 256 + c] = resid[(size_t)i * 256 + c] + acc[fm][fn][r] + bv;
                }
        }
    }
}

// ---------------------------------------------------------------- kv partials (2 j-subchunks), bf16 in
__global__ __launch_bounds__(256) void kvp_kernel(const unsigned short* __restrict__ KB,
                                                  const unsigned short* __restrict__ VB,
                                                  float* __restrict__ kvp) {
    int blk = blockIdx.x;
    int sub = blk & 1, rest = blk >> 1;
    int b = rest >> 5, n = (rest >> 3) & 3, h = rest & 7;
    int tid = threadIdx.x;
    int k = tid >> 3, d0 = (tid & 7) * 4;
    float dec = logf(1.0f - exp2f(-5.0f - (float)h));
    float lrs = (1.0f - expf(dec * (float)CHUNKN)) / (1.0f - expf(dec));
    float invl = 1.0f / lrs;
    const unsigned short* krb = KB + ((size_t)(b * NHEADS + h) * TLEN + n * CHUNKN) * KD;
    const unsigned short* vb = VB + ((size_t)(b * NHEADS + h) * TLEN + n * CHUNKN) * KD;
    float a0 = 0, a1 = 0, a2 = 0, a3 = 0;
    int j0 = sub * 250;
    for (int j = j0; j < j0 + 250; ++j) {
        float kj = bf2f(krb[(size_t)j * KD + k]);
        float vd = expf(dec * (float)(CHUNKN - 1 - j)) * invl;
        float w = kj * vd;
        u16x4 vv = *(const u16x4*)(vb + (size_t)j * KD + d0);
        a0 = fmaf(w, bf2f(vv[0]), a0); a1 = fmaf(w, bf2f(vv[1]), a1);
        a2 = fmaf(w, bf2f(vv[2]), a2); a3 = fmaf(w, bf2f(vv[3]), a3);
    }
    float* dst = kvp + ((size_t)rest * 2 + sub) * 1024 + k * 32 + d0;
    dst[0] = a0; dst[1] = a1; dst[2] = a2; dst[3] = a3;
}

// ---------------------------------------------------------------- cross-chunk scan
__global__ __launch_bounds__(256) void scan_kernel(const float* __restrict__ kvp,
                                                   float* __restrict__ rec,
                                                   float* __restrict__ sig) {
    __shared__ float cs[32];
    __shared__ float ssig;
    int blk = blockIdx.x;
    int b = blk >> 3, h = blk & 7;
    int tid = threadIdx.x;
    float dec = logf(1.0f - exp2f(-5.0f - (float)h));
    float cd = expf(dec * (float)CHUNKN);
    float S0 = 0, S1 = 0, S2 = 0, S3 = 0;
    float sigma = 1.0f;
    for (int n = 0; n < NCHUNK; ++n) {
        int rest = b * 32 + n * 8 + h;
        size_t rbase = (size_t)rest * 1024;
        size_t pbase = (size_t)rest * 2048;
        rec[rbase + tid] = S0;
        rec[rbase + tid + 256] = S1;
        rec[rbase + tid + 512] = S2;
        rec[rbase + tid + 768] = S3;
        if (tid == 0) sig[rest] = sigma;
        float k0 = 0, k1 = 0, k2 = 0, k3 = 0;
        #pragma unroll
        for (int s = 0; s < 2; ++s) {
            k0 += kvp[pbase + s * 1024 + tid];
            k1 += kvp[pbase + s * 1024 + tid + 256];
            k2 += kvp[pbase + s * 1024 + tid + 512];
            k3 += kvp[pbase + s * 1024 + tid + 768];
        }
        S0 = S0 * cd + k0;
        S1 = S1 * cd + k1;
        S2 = S2 * cd + k2;
        S3 = S3 * cd + k3;
        if (tid < 32) cs[tid] = 0.f;
        __syncthreads();
        float part = fabsf(S0) + fabsf(S1) + fabsf(S2) + fabsf(S3);
        atomicAdd(&cs[tid & 31], part);
        __syncthreads();
        if (tid == 0) {
            float m = cs[0];
            for (int d = 1; d < 32; ++d) m = fmaxf(m, cs[d]);
            ssig = fmaxf(m, 1.0f);
        }
        __syncthreads();
        sigma = ssig;
    }
}

// ---------------------------------------------------------------- retention core v3 (MFMA, bf16 in)
__global__ __launch_bounds__(256, 2) void ret_core3(
    const unsigned short* __restrict__ QH, const unsigned short* __restrict__ QL,
    const unsigned short* __restrict__ KB, const unsigned short* __restrict__ VB,
    const unsigned short* __restrict__ GB,
    const float* __restrict__ rec, const float* __restrict__ sig,
    unsigned short* __restrict__ ABH, unsigned short* __restrict__ ABL) {
    __shared__ unsigned short Kt[64][40];    // K*e^{-dec j}  [j][d]
    __shared__ unsigned short Vt[32][72];    // V^T           [d][j]
    __shared__ unsigned short SpH[32][40];   // S_prev^T hi   [d][k]
    __shared__ unsigned short SpL[32][40];   // S_prev^T lo
    __shared__ unsigned short Pl[128][72];   // P (loop) / out hi+lo (epilogue)

    const int u = 3 - (int)(blockIdx.x >> 8);
    const int chunk = blockIdx.x & 255;
    const int b = chunk >> 5, n = (chunk >> 3) & 3, h = chunk & 7;
    const int tid = threadIdx.x;
    const int wid = tid >> 6, lane = tid & 63;
    const int c = lane & 15, gq = lane >> 4;
    const float dec = logf(1.0f - exp2f(-5.0f - (float)h));
    const float ndec = -dec;
    const size_t cb16 = ((size_t)(b * NHEADS + h) * TLEN + n * CHUNKN) * KD;
    const int i0 = u * 128 + wid * 32;
    const int NT = 2 * u + 2;
    const int jtmax_w = (i0 + 31) >> 6;

    // ---- Q fragments: direct bf16 hi/lo loads
    s16x8 qh[2], ql[2];
    #pragma unroll
    for (int fi = 0; fi < 2; ++fi) {
        size_t off = cb16 + (size_t)(i0 + fi * 16 + c) * KD + gq * 8;
        qh[fi] = *(const s16x8*)(QH + off);
        ql[fi] = *(const s16x8*)(QL + off);
    }

    // ---- stage S_prev^T hi/lo (rec is [k][d] row-major fp32, 32x32)
    {
        int e0 = tid * 4;
        int k = e0 >> 5, d0 = e0 & 31;
        float4 sv = *(const float4*)(rec + (size_t)chunk * 1024 + e0);
        float se[4] = {sv.x, sv.y, sv.z, sv.w};
        #pragma unroll
        for (int j = 0; j < 4; ++j) {
            unsigned short hb = f2bf(se[j]);
            SpH[d0 + j][k] = hb;
            SpL[d0 + j][k] = f2bf(se[j] - bf2f(hb));
        }
    }

    f32x4 ot[2][2] = {};
    float absI[2] = {0.f, 0.f};

    for (int jt = 0; jt < NT; ++jt) {
        if (jt) __syncthreads();
        {   // stage K (scaled) and V^T from bf16
            int jl = tid >> 2, d0 = (tid & 3) * 8;
            int jg = jt * 64 + jl;
            float ej = expf(ndec * (float)jg);
            u16x8 kraw = *(const u16x8*)(KB + cb16 + (size_t)jg * KD + d0);
            u16x8 vraw = *(const u16x8*)(VB + cb16 + (size_t)jg * KD + d0);
            u16x8 kb;
            #pragma unroll
            for (int e = 0; e < 8; ++e) kb[e] = f2bf(bf2f(kraw[e]) * ej);
            *(u16x8*)&Kt[jl][d0] = kb;
            #pragma unroll
            for (int e = 0; e < 8; ++e) Vt[d0 + e][jl] = vraw[e];
        }
        __syncthreads();
        if (jt <= jtmax_w) {
            f32x4 st[4][2] = {};
            s16x8 ka[4];
            #pragma unroll
            for (int jf = 0; jf < 4; ++jf)
                ka[jf] = *(const s16x8*)&Kt[jf * 16 + c][gq * 8];
            #pragma unroll
            for (int jf = 0; jf < 4; ++jf)
                #pragma unroll
                for (int fi = 0; fi < 2; ++fi) {
                    st[jf][fi] = __builtin_amdgcn_mfma_f32_16x16x32_bf16(ka[jf], qh[fi], st[jf][fi], 0, 0, 0);
                    st[jf][fi] = __builtin_amdgcn_mfma_f32_16x16x32_bf16(ka[jf], ql[fi], st[jf][fi], 0, 0, 0);
                }
            const bool domask = (jt * 64 + 63 > i0);
            #pragma unroll
            for (int jf = 0; jf < 4; ++jf)
                #pragma unroll
                for (int fi = 0; fi < 2; ++fi) {
                    const int ii = i0 + fi * 16 + c;
                    if (domask) {
                        #pragma unroll
                        for (int r = 0; r < 4; ++r) {
                            int jg = jt * 64 + jf * 16 + gq * 4 + r;
                            if (jg > ii) st[jf][fi][r] = 0.f;
                        }
                    }
                    absI[fi] += (fabsf(st[jf][fi][0]) + fabsf(st[jf][fi][1])) +
                                (fabsf(st[jf][fi][2]) + fabsf(st[jf][fi][3]));
                    uint2 pw;
                    pw.x = cvtpk(st[jf][fi][0], st[jf][fi][1]);
                    pw.y = cvtpk(st[jf][fi][2], st[jf][fi][3]);
                    *(uint2*)&Pl[wid * 32 + fi * 16 + c][jf * 16 + gq * 4] = pw;
                }
            #pragma unroll
            for (int js = 0; js < 2; ++js) {
                s16x8 va0 = *(const s16x8*)&Vt[c][js * 32 + gq * 8];
                s16x8 va1 = *(const s16x8*)&Vt[16 + c][js * 32 + gq * 8];
                #pragma unroll
                for (int fi = 0; fi < 2; ++fi) {
                    s16x8 pb = *(const s16x8*)&Pl[wid * 32 + fi * 16 + c][js * 32 + gq * 8];
                    ot[0][fi] = __builtin_amdgcn_mfma_f32_16x16x32_bf16(va0, pb, ot[0][fi], 0, 0, 0);
                    ot[1][fi] = __builtin_amdgcn_mfma_f32_16x16x32_bf16(va1, pb, ot[1][fi], 0, 0, 0);
                }
            }
        }
    }

    // ---- cross term X^T = S_prev^T · Q
    f32x4 xt[2][2] = {};
    #pragma unroll
    for (int fd = 0; fd < 2; ++fd) {
        s16x8 sh = *(const s16x8*)&SpH[fd * 16 + c][gq * 8];
        s16x8 sl = *(const s16x8*)&SpL[fd * 16 + c][gq * 8];
        #pragma unroll
        for (int fi = 0; fi < 2; ++fi) {
            xt[fd][fi] = __builtin_amdgcn_mfma_f32_16x16x32_bf16(sh, qh[fi], xt[fd][fi], 0, 0, 0);
            xt[fd][fi] = __builtin_amdgcn_mfma_f32_16x16x32_bf16(sh, ql[fi], xt[fd][fi], 0, 0, 0);
            xt[fd][fi] = __builtin_amdgcn_mfma_f32_16x16x32_bf16(sl, qh[fi], xt[fd][fi], 0, 0, 0);
        }
    }

    // ---- per-row scales + combine + group-norm + silu(g bf16) -> Pl
    const float er = expf(dec);
    const float inv1mr = 1.0f / (1.0f - er);
    const float lrs = (1.0f - expf(dec * (float)CHUNKN)) * inv1mr;
    const float sgp = sig[chunk];
    #pragma unroll
    for (int fi = 0; fi < 2; ++fi) {
        absI[fi] += __shfl_xor(absI[fi], 16);
        absI[fi] += __shfl_xor(absI[fi], 32);
        const int ii = i0 + fi * 16 + c;
        float rowsum = (1.0f - expf(dec * (float)(ii + 1))) * inv1mr;
        float iscale = rsqrtf(rowsum);
        float f_i = expf(dec * (float)ii) * iscale;
        float inner = fmaxf(absI[fi] * f_i, 1.0f);
        float alls = fmaxf(inner, sgp);
        float qd = expf(dec * (float)(ii + 1)) * lrs * iscale;
        float inva = 1.0f / alls;
        float vals[2][4];
        float ms = 0.f;
        #pragma unroll
        for (int fd = 0; fd < 2; ++fd)
            #pragma unroll
            for (int r = 0; r < 4; ++r) {
                float t = (ot[fd][fi][r] * f_i + xt[fd][fi][r] * qd) * inva;
                vals[fd][r] = t;
                ms += t * t;
            }
        ms += __shfl_xor(ms, 16);
        ms += __shfl_xor(ms, 32);
        float rn = rsqrtf(ms * (1.0f / 32.0f) + 1e-6f);
        const int tg = n * CHUNKN + ii;
        const unsigned short* gp = GB + ((size_t)b * TLEN + tg) * 256 + h * KD;
        #pragma unroll
        for (int fd = 0; fd < 2; ++fd) {
            u16x4 gv = *(const u16x4*)(gp + fd * 16 + gq * 4);
            unsigned short hb[4], lb[4];
            #pragma unroll
            for (int r = 0; r < 4; ++r) {
                float ge = bf2f(gv[r]);
                float sg = ge / (1.0f + expf(-ge));
                float ov = sg * vals[fd][r] * rn;
                hb[r] = f2bf(ov);
                lb[r] = f2bf(ov - bf2f(hb[r]));
            }
            uint2 ph, plw;
            ph.x = (unsigned int)hb[0] | ((unsigned int)hb[1] << 16);
            ph.y = (unsigned int)hb[2] | ((unsigned int)hb[3] << 16);
            plw.x = (unsigned int)lb[0] | ((unsigned int)lb[1] << 16);
            plw.y = (unsigned int)lb[2] | ((unsigned int)lb[3] << 16);
            *(uint2*)&Pl[wid * 32 + fi * 16 + c][fd * 16 + gq * 4] = ph;
            *(uint2*)&Pl[wid * 32 + fi * 16 + c][36 + fd * 16 + gq * 4] = plw;
        }
    }
    __syncthreads();
    {
        int r = tid & 127, half = tid >> 7;
        int ig = u * 128 + r;
        if (ig < CHUNKN) {
            unsigned short* D = half ? ABL : ABH;
            size_t dst = ((size_t)b * TLEN + n * CHUNKN + ig) * 256 + h * KD;
            #pragma unroll
            for (int k = 0; k < 4; ++k) {
                u16x4 a = *(const u16x4*)&Pl[r][half * 36 + k * 8];
                u16x4 bq = *(const u16x4*)&Pl[r][half * 36 + k * 8 + 4];
                u16x8 w;
                w[0] = a[0]; w[1] = a[1]; w[2] = a[2]; w[3] = a[3];
                w[4] = bq[0]; w[5] = bq[1]; w[6] = bq[2]; w[7] = bq[3];
                *(u16x8*)(D + dst + k * 8) = w;
            }
        }
    }
}

// ---------------------------------------------------------------- tiny MHA (seq len 4), bf16 in -> bf16 hi/lo out
__global__ __launch_bounds__(256) void mha_attn(const unsigned short* __restrict__ qh_,
                                                const unsigned short* __restrict__ kh_,
                                                const unsigned short* __restrict__ vh_,
                                                unsigned short* __restrict__ OH,
                                                unsigned short* __restrict__ OL) {
    int gidx = blockIdx.x * 256 + threadIdx.x;
    if (gidx >= 2 * TLEN * NHEADS * 4) return;
    int i = gidx & 3;
    int h = (gidx >> 2) & 7;
    int rest = gidx >> 5;  // b*2000 + t
    int t = rest % TLEN;
    int b = rest / TLEN;
    size_t rows[4];
    #pragma unroll
    for (int c = 0; c < 4; ++c) rows[c] = ((size_t)(b * 4 + c) * TLEN + t);
    float q[32];
    #pragma unroll
    for (int rb = 0; rb < 4; ++rb) {
        u16x8 t8 = *(const u16x8*)(qh_ + rows[i] * 256 + h * 32 + rb * 8);
        #pragma unroll
        for (int e = 0; e < 8; ++e) q[rb * 8 + e] = bf2f(t8[e]);
    }
    float s[4];
    #pragma unroll
    for (int j = 0; j < 4; ++j) {
        const unsigned short* kp = kh_ + rows[j] * 256 + h * 32;
        float a0 = 0, a1 = 0, a2 = 0, a3 = 0;
        #pragma unroll
        for (int rb = 0; rb < 4; ++rb) {
            u16x8 t8 = *(const u16x8*)(kp + rb * 8);
            a0 = fmaf(q[rb * 8 + 0], bf2f(t8[0]), a0);
            a1 = fmaf(q[rb * 8 + 1], bf2f(t8[1]), a1);
            a2 = fmaf(q[rb * 8 + 2], bf2f(t8[2]), a2);
            a3 = fmaf(q[rb * 8 + 3], bf2f(t8[3]), a3);
            a0 = fmaf(q[rb * 8 + 4], bf2f(t8[4]), a0);
            a1 = fmaf(q[rb * 8 + 5], bf2f(t8[5]), a1);
            a2 = fmaf(q[rb * 8 + 6], bf2f(t8[6]), a2);
            a3 = fmaf(q[rb * 8 + 7], bf2f(t8[7]), a3);
        }
        s[j] = (a0 + a1) + (a2 + a3);
    }
    float m = fmaxf(fmaxf(s[0], s[1]), fmaxf(s[2], s[3]));
    float p[4], den = 0.f;
    #pragma unroll
    for (int j = 0; j < 4; ++j) { p[j] = expf(s[j] - m); den += p[j]; }
    float inv = 1.0f / den;
    float o[32];
    #pragma unroll
    for (int e = 0; e < 32; ++e) o[e] = 0.f;
    #pragma unroll
    for (int j = 0; j < 4; ++j) {
        float wj = p[j] * inv;
        const unsigned short* vp = vh_ + rows[j] * 256 + h * 32;
        #pragma unroll
        for (int rb = 0; rb < 4; ++rb) {
            u16x8 t8 = *(const u16x8*)(vp + rb * 8);
            #pragma unroll
            for (int e = 0; e < 8; ++e)
                o[rb * 8 + e] = fmaf(wj, bf2f(t8[e]), o[rb * 8 + e]);
        }
    }
    #pragma unroll
    for (int rb = 0; rb < 8; ++rb) {
        u16x4 hv, lv;
        #pragma unroll
        for (int e = 0; e < 4; ++e) {
            float x = o[rb * 4 + e];
            hv[e] = f2bf(x);
            lv[e] = f2bf(x - bf2f(hv[e]));
        }
        *(u16x4*)(OH + rows[i] * 256 + h * 32 + rb * 4) = hv;
        *(u16x4*)(OL + rows[i] * 256 + h * 32 + rb * 4) = lv;
    }
}

// ---------------------------------------------------------------- launch
extern "C" void kernel_launch(void* const* d_in, const int* in_sizes, int n_in,
                              void* d_out, int out_size, void* d_ws, size_t ws_size,
                              hipStream_t stream) {
    (void)in_sizes; (void)n_in; (void)out_size; (void)ws_size;
    const float* x    = (const float*)d_in[0];
    const float* ln1g = (const float*)d_in[1];
    const float* ln1b = (const float*)d_in[2];
    const float* ln2g = (const float*)d_in[3];
    const float* ln2b = (const float*)d_in[4];
    const float* qw   = (const float*)d_in[5];
    const float* kw   = (const float*)d_in[6];
    const float* vw   = (const float*)d_in[7];
    const float* gw   = (const float*)d_in[8];
    const float* ow   = (const float*)d_in[9];
    const float* in_w = (const float*)d_in[10];
    const float* in_b = (const float*)d_in[11];
    const float* outw = (const float*)d_in[12];
    const float* outb = (const float*)d_in[13];
    float* out = (float*)d_out;
    float* ws = (float*)d_ws;

    // workspace layout (float units), total 14,957,312 fl = 59.8 MB
    constexpr size_t O_SIN = 0;                    // 32000
    constexpr size_t O_COS = 32000;                // 32000
    constexpr size_t O_W   = 64000;                // 294912 (bf16 weights)
    constexpr size_t O_QH  = 358912;               // 2048000 | x2 overlay (QH+QL)
    constexpr size_t O_QL  = O_QH + 2048000;       // 2048000
    constexpr size_t O_KB  = O_QL + 2048000;       // 2048000 | qhat overlay
    constexpr size_t O_VB  = O_KB + 2048000;       // 2048000 | khat overlay
    constexpr size_t O_GB  = O_VB + 2048000;       // 2048000 | vhat overlay
    constexpr size_t O_H   = O_GB + 2048000;       // 2048000 | kvp overlay
    constexpr size_t O_L   = O_H + 2048000;        // 2048000
    constexpr size_t O_REC = O_L + 2048000;        // 262144
    constexpr size_t O_SIG = O_REC + 262144;       // 256

    float* sinT = ws + O_SIN;
    float* cosT = ws + O_COS;
    unsigned short* Wc = (unsigned short*)(ws + O_W);
    unsigned short* QH = (unsigned short*)(ws + O_QH);
    unsigned short* QL = (unsigned short*)(ws + O_QL);
    unsigned short* KB = (unsigned short*)(ws + O_KB);
    unsigned short* VB = (unsigned short*)(ws + O_VB);
    unsigned short* GB = (unsigned short*)(ws + O_GB);
    unsigned short* H  = (unsigned short*)(ws + O_H);
    unsigned short* L  = (unsigned short*)(ws + O_L);
    float* x2   = ws + O_QH;   // overlay QH+QL (dead after ret_core3)
    unsigned short* qhat = KB; // overlays dead after ret_core3
    unsigned short* khat = VB;
    unsigned short* vhat = GB;
    float* kvpf = ws + O_H;    // overlay H (dead between proj and ret_core3)
    float* recb = ws + O_REC;
    float* sigb = ws + O_SIG;

    tab_kernel<<<125, 256, 0, stream>>>(sinT, cosT);
    wcast_kernel<<<576, 256, 0, stream>>>(qw, kw, vw, gw, ow, in_w, outw, Wc);
    // 1) LN1: x -> H/L
    ln_kernel<<<MROWS / 4, 256, 0, stream>>>(x, ln1g, ln1b, H, L, MROWS);
    // 2) proj -> QH/QL (q hi/lo), KB, VB (head layout), GB (row layout)
    gemm_mfma<0><<<dim3(8, 125), 256, 0, stream>>>(H, L, Wc, sinT, cosT, nullptr,
                                                   nullptr, nullptr, QH, QL, KB, VB, GB);
    // 3) kv partials (bf16 in) -> kvpf
    kvp_kernel<<<512, 256, 0, stream>>>(KB, VB, kvpf);
    // 4) scan -> rec, sig
    scan_kernel<<<64, 256, 0, stream>>>(kvpf, recb, sigb);
    // 5) retention core -> H/L (ab hi/lo)
    ret_core3<<<1024, 256, 0, stream>>>(QH, QL, KB, VB, GB, recb, sigb, H, L);
    // 6) out-proj + residual -> x2
    gemm_mfma<1><<<dim3(2, 125), 256, 0, stream>>>(H, L, Wc, nullptr, nullptr,
                                                   nullptr, x, x2,
                                                   nullptr, nullptr, nullptr, nullptr, nullptr);
    // 7) LN2: x2 -> H/L
    ln_kernel<<<MROWS / 4, 256, 0, stream>>>(x2, ln2g, ln2b, H, L, MROWS);
    // 8) qkv -> qhat/khat/vhat (bf16 row layout)
    gemm_mfma<2><<<dim3(6, 125), 256, 0, stream>>>(H, L, Wc, nullptr, nullptr,
                                                   in_b, nullptr, nullptr,
                                                   qhat, khat, vhat, nullptr, nullptr);
    // 9) tiny attention -> H/L (att hi/lo)
    mha_attn<<<500, 256, 0, stream>>>(qhat, khat, vhat, H, L);
    // 10) final: x2 + att @ out_w.T + out_b -> d_out
    gemm_mfma<3><<<dim3(2, 125), 256, 0, stream>>>(H, L, Wc, nullptr, nullptr,
                                                   outb, x2, out,
                                                   nullptr, nullptr, nullptr, nullptr, nullptr);
}